// Round 1
// baseline (7114.533 us; speedup 1.0000x reference)
//
#include <hip/hip_runtime.h>

#define T   4
#define C   256
#define H   48
#define W   48
#define HW  (H*W)          // 2304
#define K   25
#define DG  4
#define CG  64             // C / DG
#define OFFC 200           // DG*2*K
#define CK  6400           // C*K
#define CKT 6912           // C*27 (temporal)

__device__ inline unsigned short f2bf(float f) {
    unsigned int u = __float_as_uint(f);
    unsigned int r = (u + 0x7FFFu + ((u >> 16) & 1u)) >> 16;
    return (unsigned short)r;
}
__device__ inline float bf2f(unsigned short u) {
    return __uint_as_float(((unsigned int)u) << 16);
}

// ---------------------------------------------------------------------------
// K1: offset conv. offset[oc][t][h][w] = sum_c sum_{kh,kw} x[c][t][h+kh-2][w+kw-2] * w_off[oc][c][kh][kw]
// Stored as off_buf[t][oc][p].  Block: 192 thr = 16 rows x 12 quad-cols, 4 px/thread.
// ---------------------------------------------------------------------------
__global__ __launch_bounds__(192) void offset_conv_k(const float* __restrict__ x,
                                                     const float* __restrict__ w_off,
                                                     float* __restrict__ off_buf) {
    __shared__ float wl[CK];                  // 25.6 KB
    const int tile = blockIdx.x;              // 0..2 -> rows [16*tile, 16*tile+16)
    const int oc   = blockIdx.y;              // 0..199
    const int t    = blockIdx.z;              // 0..3
    for (int i = threadIdx.x; i < CK; i += 192) wl[i] = w_off[(size_t)oc * CK + i];
    __syncthreads();

    const int r  = threadIdx.x / 12;
    const int q  = threadIdx.x % 12;
    const int h  = tile * 16 + r;
    const int w0 = q * 4;

    float acc[4] = {0.f, 0.f, 0.f, 0.f};
    for (int c = 0; c < C; ++c) {
        const float* xp = x + (size_t)(c * T + t) * HW;
        const float* wp = wl + c * K;
        #pragma unroll
        for (int kh = 0; kh < 5; ++kh) {
            const int y = h + kh - 2;
            if (y < 0 || y >= H) continue;
            const float* xr = xp + y * W;
            float seg[8];
            #pragma unroll
            for (int i = 0; i < 8; ++i) {
                const int xx = w0 + i - 2;
                seg[i] = (xx >= 0 && xx < W) ? xr[xx] : 0.f;
            }
            #pragma unroll
            for (int kw = 0; kw < 5; ++kw) {
                const float wv = wp[kh * 5 + kw];
                #pragma unroll
                for (int j = 0; j < 4; ++j) acc[j] = fmaf(seg[kw + j], wv, acc[j]);
            }
        }
    }
    const int p = h * W + w0;
    *(float4*)(off_buf + (size_t)(t * OFFC + oc) * HW + p) =
        make_float4(acc[0], acc[1], acc[2], acc[3]);
}

// ---------------------------------------------------------------------------
// K2: bilinear sampling -> samp[t][c*25+k][p] as bf16 (im2col B matrix for K3).
// grid: (9 tiles of 256 px, k=25, z = t*4+g)
// ---------------------------------------------------------------------------
__global__ __launch_bounds__(256) void sample_k(const float* __restrict__ x,
                                                const float* __restrict__ off_buf,
                                                unsigned short* __restrict__ samp) {
    const int tile = blockIdx.x;
    const int k    = blockIdx.y;
    const int g    = blockIdx.z & 3;
    const int t    = blockIdx.z >> 2;
    const int p    = tile * 256 + threadIdx.x;
    const int h    = p / W;
    const int w    = p % W;
    const int pos  = g * K + k;

    const float dy = off_buf[(size_t)(t * OFFC + pos * 2 + 0) * HW + p];
    const float dx = off_buf[(size_t)(t * OFFC + pos * 2 + 1) * HW + p];
    const int ky = k / 5, kx = k % 5;
    const float sy = (float)(h + ky - 2) + dy;
    const float sx = (float)(w + kx - 2) + dx;
    const float y0f = floorf(sy), x0f = floorf(sx);
    const float wy = sy - y0f, wx = sx - x0f;
    const int y0 = (int)y0f, x0 = (int)x0f;
    const int y1 = y0 + 1,  x1 = x0 + 1;
    const bool vy0 = (y0 >= 0) & (y0 < H);
    const bool vy1 = (y1 >= 0) & (y1 < H);
    const bool vx0 = (x0 >= 0) & (x0 < W);
    const bool vx1 = (x1 >= 0) & (x1 < W);
    float w00 = (1.f - wy) * (1.f - wx);
    float w01 = (1.f - wy) * wx;
    float w10 = wy * (1.f - wx);
    float w11 = wy * wx;
    if (!(vy0 && vx0)) w00 = 0.f;
    if (!(vy0 && vx1)) w01 = 0.f;
    if (!(vy1 && vx0)) w10 = 0.f;
    if (!(vy1 && vx1)) w11 = 0.f;
    const int yc0 = min(max(y0, 0), H - 1), yc1 = min(max(y1, 0), H - 1);
    const int xc0 = min(max(x0, 0), W - 1), xc1 = min(max(x1, 0), W - 1);
    const int i00 = yc0 * W + xc0, i01 = yc0 * W + xc1;
    const int i10 = yc1 * W + xc0, i11 = yc1 * W + xc1;

    for (int cg = 0; cg < CG; ++cg) {
        const int c = g * CG + cg;
        const float* xp = x + (size_t)(c * T + t) * HW;
        const float v = w00 * xp[i00] + w01 * xp[i01] + w10 * xp[i10] + w11 * xp[i11];
        samp[((size_t)t * CK + (size_t)(c * K + k)) * HW + p] = f2bf(v);
    }
}

// ---------------------------------------------------------------------------
// K3: fp32 GEMM  out[o][t][p] = sum_r w_def[o][r] * samp[t][r][p]   (r = c*25+k)
// 64x64 tile per block, 256 thr (16x16), 4x4 micro-tile, 16-deep K staging.
// grid: (36 p-tiles, 4 o-tiles, 4 t)
// ---------------------------------------------------------------------------
__global__ __launch_bounds__(256) void gemm_def_k(const float* __restrict__ w_def,
                                                  const unsigned short* __restrict__ samp,
                                                  float* __restrict__ out) {
    __shared__ float As[16][64];
    __shared__ float Bs[16][64];
    const int t  = blockIdx.z;
    const int o0 = blockIdx.y * 64;
    const int p0 = blockIdx.x * 64;
    const unsigned short* sb = samp + (size_t)t * CK * HW;
    const int tid = threadIdx.x;
    const int ty = tid >> 4, tx = tid & 15;
    const int aoo = tid >> 2, aks = (tid & 3) * 4;   // A tile load coords
    const int bkb = tid >> 4, bps = (tid & 15) * 4;  // B tile load coords

    float acc[4][4] = {};
    for (int kk = 0; kk < CK; kk += 16) {
        const float4  av = *(const float4*)(w_def + (size_t)(o0 + aoo) * CK + kk + aks);
        const ushort4 bv = *(const ushort4*)(sb + (size_t)(kk + bkb) * HW + p0 + bps);
        __syncthreads();
        As[aks + 0][aoo] = av.x;
        As[aks + 1][aoo] = av.y;
        As[aks + 2][aoo] = av.z;
        As[aks + 3][aoo] = av.w;
        Bs[bkb][bps + 0] = bf2f(bv.x);
        Bs[bkb][bps + 1] = bf2f(bv.y);
        Bs[bkb][bps + 2] = bf2f(bv.z);
        Bs[bkb][bps + 3] = bf2f(bv.w);
        __syncthreads();
        #pragma unroll
        for (int kb = 0; kb < 16; ++kb) {
            const float4 a = *(const float4*)(&As[kb][ty * 4]);
            const float4 b = *(const float4*)(&Bs[kb][tx * 4]);
            const float ar[4] = {a.x, a.y, a.z, a.w};
            const float br[4] = {b.x, b.y, b.z, b.w};
            #pragma unroll
            for (int i = 0; i < 4; ++i)
                #pragma unroll
                for (int j = 0; j < 4; ++j)
                    acc[i][j] = fmaf(ar[i], br[j], acc[i][j]);
        }
    }
    #pragma unroll
    for (int i = 0; i < 4; ++i) {
        const int o = o0 + ty * 4 + i;
        *(float4*)(out + (size_t)(o * T + t) * HW + p0 + tx * 4) =
            make_float4(acc[i][0], acc[i][1], acc[i][2], acc[i][3]);
    }
}

// ---------------------------------------------------------------------------
// K4: temporal 3x3x3 conv + bias, out += .  Block: 192 thr, 4 px/thread.
// grid: (3 row-tiles, t=4, o=256)
// ---------------------------------------------------------------------------
__global__ __launch_bounds__(192) void temporal_k(const float* __restrict__ x,
                                                  const float* __restrict__ w_temp,
                                                  const float* __restrict__ b_temp,
                                                  float* __restrict__ out) {
    __shared__ float wl[CKT];                 // 27.6 KB
    const int tile = blockIdx.x;
    const int t    = blockIdx.y;
    const int o    = blockIdx.z;
    for (int i = threadIdx.x; i < CKT; i += 192) wl[i] = w_temp[(size_t)o * CKT + i];
    __syncthreads();

    const int r  = threadIdx.x / 12;
    const int q  = threadIdx.x % 12;
    const int h  = tile * 16 + r;
    const int w0 = q * 4;
    const float bias = b_temp[o];

    float acc[4] = {bias, bias, bias, bias};
    for (int c = 0; c < C; ++c) {
        #pragma unroll
        for (int kt = 0; kt < 3; ++kt) {
            const int tt = t + kt - 1;
            if (tt < 0 || tt >= T) continue;
            const float* xp = x + (size_t)(c * T + tt) * HW;
            const float* wp = wl + (c * 3 + kt) * 9;
            #pragma unroll
            for (int kh = 0; kh < 3; ++kh) {
                const int y = h + kh - 1;
                if (y < 0 || y >= H) continue;
                const float* xr = xp + y * W;
                float seg[6];
                #pragma unroll
                for (int i = 0; i < 6; ++i) {
                    const int xx = w0 + i - 1;
                    seg[i] = (xx >= 0 && xx < W) ? xr[xx] : 0.f;
                }
                #pragma unroll
                for (int kw = 0; kw < 3; ++kw) {
                    const float wv = wp[kh * 3 + kw];
                    #pragma unroll
                    for (int j = 0; j < 4; ++j) acc[j] = fmaf(seg[kw + j], wv, acc[j]);
                }
            }
        }
    }
    float4* op = (float4*)(out + (size_t)(o * T + t) * HW + h * W + w0);
    float4 v = *op;
    v.x += acc[0]; v.y += acc[1]; v.z += acc[2]; v.w += acc[3];
    *op = v;
}

extern "C" void kernel_launch(void* const* d_in, const int* in_sizes, int n_in,
                              void* d_out, int out_size, void* d_ws, size_t ws_size,
                              hipStream_t stream) {
    const float* x      = (const float*)d_in[0];
    const float* w_off  = (const float*)d_in[1];
    const float* w_def  = (const float*)d_in[2];
    const float* w_temp = (const float*)d_in[3];
    const float* b_temp = (const float*)d_in[4];
    float* out = (float*)d_out;

    // workspace layout
    float* off_buf = (float*)d_ws;                                   // 4*200*2304 f32 = 7.37 MB
    unsigned short* samp = (unsigned short*)((char*)d_ws + (size_t)T * OFFC * HW * sizeof(float));
                                                                     // 4*6400*2304 bf16 = 118 MB

    offset_conv_k<<<dim3(3, OFFC, T), 192, 0, stream>>>(x, w_off, off_buf);
    sample_k<<<dim3(9, K, T * DG), 256, 0, stream>>>(x, off_buf, samp);
    gemm_def_k<<<dim3(HW / 64, C / 64, T), 256, 0, stream>>>(w_def, samp, out);
    temporal_k<<<dim3(3, T, C), 192, 0, stream>>>(x, w_temp, b_temp, out);
}

// Round 2
// 1144.102 us; speedup vs baseline: 6.2184x; 6.2184x over previous
//
#include <hip/hip_runtime.h>

#define T    4
#define C    256
#define H    48
#define W    48
#define HW   2304
#define DG   4
#define OFFC 200
#define CK5  6400      // K for offset & deform GEMMs, layout (k,c) c-inner
#define CK9  2304      // K for temporal per-kt GEMMs, layout (j,c) c-inner
#define NFULL 9216     // T*HW

typedef __attribute__((ext_vector_type(8))) short bf16x8;
typedef __attribute__((ext_vector_type(4))) float f32x4;

__device__ __forceinline__ unsigned short f2bf(float f) {
    unsigned int u = __float_as_uint(f);
    return (unsigned short)((u + 0x7FFFu + ((u >> 16) & 1u)) >> 16);
}
__device__ __forceinline__ float bf2f(unsigned short u) {
    return __uint_as_float(((unsigned int)u) << 16);
}
__device__ __forceinline__ void gload16(const void* g, void* l) {
    __builtin_amdgcn_global_load_lds(
        (const __attribute__((address_space(1))) unsigned int*)g,
        (__attribute__((address_space(3))) unsigned int*)l, 16, 0, 0);
}

// ---------------------------------------------------------------------------
// Weight re-layout casts (fp32 -> bf16, K-major (k,c) ordering, c inner).
// ---------------------------------------------------------------------------
__global__ __launch_bounds__(256) void cast5_k(const float* __restrict__ w,
                                               unsigned short* __restrict__ a, int mvalid) {
    const int idx = blockIdx.x * 256 + threadIdx.x;      // < 256*6400
    const int c = idx & 255, rest = idx >> 8;
    const int q = rest % 25, o = rest / 25;
    a[idx] = (o < mvalid) ? f2bf(w[((unsigned long)o * 256 + c) * 25 + q]) : (unsigned short)0;
}
// wb layout: 3 A-matrices [kt][256][(j,c)], j = kh*3+kw
__global__ __launch_bounds__(256) void cast_temp_k(const float* __restrict__ w,
                                                   unsigned short* __restrict__ a) {
    const int idx = blockIdx.x * 256 + threadIdx.x;      // < 3*256*2304
    const int c = idx & 255, rest = idx >> 8;
    const int j = rest % 9, oo = rest / 9;
    const int o = oo & 255, kt = oo >> 8;
    a[idx] = f2bf(w[((unsigned long)o * 256 + c) * 27 + kt * 9 + j]);
}

// ---------------------------------------------------------------------------
// im2col 5x5 (pad 2): big[(t,p)][q*256+c] = x[c][t][h+qy-2][w+qx-2] (0 OOB)
// ---------------------------------------------------------------------------
__global__ __launch_bounds__(256) void im2col5_k(const float* __restrict__ x,
                                                 unsigned short* __restrict__ big) {
    const int t = blockIdx.y, p0 = blockIdx.x * 64;
    const int px = threadIdx.x & 63, sub = threadIdx.x >> 6;
    const int p = p0 + px, h = p / 48, w = p - h * 48;
    unsigned short* orow = big + ((unsigned long)t * HW + p) * CK5;
    for (int q = 0; q < 25; ++q) {
        const int qy = q / 5, qx = q - qy * 5;
        const int y = h + qy - 2, xx = w + qx - 2;
        const bool valid = (y >= 0) & (y < 48) & (xx >= 0) & (xx < 48);
        const int idx = valid ? (y * 48 + xx) : 0;
        for (int it = 0; it < 8; ++it) {
            const int cgrp = sub + it * 4;
            unsigned int pk[4];
            #pragma unroll
            for (int d = 0; d < 4; ++d) {
                const int c0 = cgrp * 8 + d * 2;
                const float v0 = valid ? x[((unsigned long)c0 * T + t) * HW + idx] : 0.f;
                const float v1 = valid ? x[((unsigned long)(c0 + 1) * T + t) * HW + idx] : 0.f;
                pk[d] = (unsigned int)f2bf(v0) | ((unsigned int)f2bf(v1) << 16);
            }
            *(uint4*)(orow + q * 256 + cgrp * 8) = make_uint4(pk[0], pk[1], pk[2], pk[3]);
        }
    }
}

// im2col 3x3 (pad 1): big[(t,p)][j*256+c]
__global__ __launch_bounds__(256) void im2col9_k(const float* __restrict__ x,
                                                 unsigned short* __restrict__ big) {
    const int t = blockIdx.y, p0 = blockIdx.x * 64;
    const int px = threadIdx.x & 63, sub = threadIdx.x >> 6;
    const int p = p0 + px, h = p / 48, w = p - h * 48;
    unsigned short* orow = big + ((unsigned long)t * HW + p) * CK9;
    for (int q = 0; q < 9; ++q) {
        const int qy = q / 3, qx = q - qy * 3;
        const int y = h + qy - 1, xx = w + qx - 1;
        const bool valid = (y >= 0) & (y < 48) & (xx >= 0) & (xx < 48);
        const int idx = valid ? (y * 48 + xx) : 0;
        for (int it = 0; it < 8; ++it) {
            const int cgrp = sub + it * 4;
            unsigned int pk[4];
            #pragma unroll
            for (int d = 0; d < 4; ++d) {
                const int c0 = cgrp * 8 + d * 2;
                const float v0 = valid ? x[((unsigned long)c0 * T + t) * HW + idx] : 0.f;
                const float v1 = valid ? x[((unsigned long)(c0 + 1) * T + t) * HW + idx] : 0.f;
                pk[d] = (unsigned int)f2bf(v0) | ((unsigned int)f2bf(v1) << 16);
            }
            *(uint4*)(orow + q * 256 + cgrp * 8) = make_uint4(pk[0], pk[1], pk[2], pk[3]);
        }
    }
}

// ---------------------------------------------------------------------------
// Sampler: big[(t,p)][k*256+c] = bilinear(x[c][t], pos(t,p,g(c),k)), bf16.
// Positions precomputed once per (p-tile) into LDS, reused across 64 c's.
// ---------------------------------------------------------------------------
__global__ __launch_bounds__(256) void sample_k(const float* __restrict__ x,
                                                const unsigned short* __restrict__ off,
                                                unsigned short* __restrict__ big) {
    __shared__ float2 pw[6400];
    __shared__ short2 pi[6400];
    const int t = blockIdx.y, p0 = blockIdx.x * 64;
    const int tid = threadIdx.x;

    for (int e = tid; e < 6400; e += 256) {   // e = ((g*25+k)*64)+px
        const int px = e & 63, gk = e >> 6;
        const int g = gk / 25, k = gk - g * 25;
        const int p = p0 + px, h = p / 48, w = p - h * 48;
        const float dy = bf2f(off[(unsigned long)(g * 50 + 2 * k) * NFULL + t * HW + p]);
        const float dx = bf2f(off[(unsigned long)(g * 50 + 2 * k + 1) * NFULL + t * HW + p]);
        const int ky = k / 5, kx = k - ky * 5;
        const float sy = (float)(h + ky - 2) + dy;
        const float sx = (float)(w + kx - 2) + dx;
        const float y0f = floorf(sy), x0f = floorf(sx);
        pw[e] = make_float2(sy - y0f, sx - x0f);
        pi[e] = make_short2((short)y0f, (short)x0f);
    }
    __syncthreads();

    const int px = tid & 63, sub = tid >> 6;
    const int p = p0 + px;
    unsigned short* orow = big + ((unsigned long)t * HW + p) * CK5;
    for (int k = 0; k < 25; ++k) {
        for (int it = 0; it < 8; ++it) {
            const int cgrp = sub + it * 4;
            const int g = cgrp >> 3;
            const int e = (g * 25 + k) * 64 + px;
            const float2 wyx = pw[e];
            const short2 yx = pi[e];
            const int y0 = yx.x, x0 = yx.y, y1 = y0 + 1, x1 = x0 + 1;
            const float wy = wyx.x, wx = wyx.y;
            float w00 = (1.f - wy) * (1.f - wx);
            float w01 = (1.f - wy) * wx;
            float w10 = wy * (1.f - wx);
            float w11 = wy * wx;
            const bool vy0 = (y0 >= 0) & (y0 < 48);
            const bool vy1 = (y1 >= 0) & (y1 < 48);
            const bool vx0 = (x0 >= 0) & (x0 < 48);
            const bool vx1 = (x1 >= 0) & (x1 < 48);
            if (!(vy0 & vx0)) w00 = 0.f;
            if (!(vy0 & vx1)) w01 = 0.f;
            if (!(vy1 & vx0)) w10 = 0.f;
            if (!(vy1 & vx1)) w11 = 0.f;
            const int yc0 = min(max(y0, 0), 47), yc1 = min(max(y1, 0), 47);
            const int xc0 = min(max(x0, 0), 47), xc1 = min(max(x1, 0), 47);
            const int i00 = yc0 * 48 + xc0, i01 = yc0 * 48 + xc1;
            const int i10 = yc1 * 48 + xc0, i11 = yc1 * 48 + xc1;
            unsigned int pk[4];
            #pragma unroll
            for (int d = 0; d < 4; ++d) {
                unsigned int lo = 0, hi = 0;
                #pragma unroll
                for (int s = 0; s < 2; ++s) {
                    const int c = cgrp * 8 + d * 2 + s;
                    const float* xc = x + ((unsigned long)c * T + t) * HW;
                    const float v = w00 * xc[i00] + w01 * xc[i01] + w10 * xc[i10] + w11 * xc[i11];
                    if (s == 0) lo = f2bf(v); else hi = f2bf(v);
                }
                pk[d] = lo | (hi << 16);
            }
            *(uint4*)(orow + k * 256 + cgrp * 8) = make_uint4(pk[0], pk[1], pk[2], pk[3]);
        }
    }
}

// ---------------------------------------------------------------------------
// m97-style MFMA GEMM: C[o][n] (ld 9216) = A[o][k] * B[n][k]^T, bf16 inputs.
// 128x128 tile, BK=32, global_load_lds(16B), mfma_f32_16x16x32_bf16.
// MODE 0: store bf16. MODE 1: store fp32 + bias. MODE 2: fp32 +=.
// ---------------------------------------------------------------------------
template <int MODE>
__global__ __launch_bounds__(256) void gemm_k(const unsigned short* __restrict__ A,
                                              const unsigned short* __restrict__ B,
                                              void* __restrict__ Cv,
                                              const float* __restrict__ bias,
                                              int Kd, int Mvalid) {
    __shared__ unsigned short Asl[128 * 32];
    __shared__ unsigned short Bsl[128 * 32];
    const int tid = threadIdx.x;
    const int wave = tid >> 6, lane = tid & 63;
    const int quad = lane >> 4, l16 = lane & 15;
    const int n0 = blockIdx.x * 128, m0 = blockIdx.y * 128;
    const int wm = (wave & 1) * 64, wn = (wave >> 1) * 64;

    const int r = lane >> 2;
    const unsigned long colb = (unsigned long)(lane & 3) * 16;
    const char* Ab = (const char*)A + ((unsigned long)(m0 + wave * 32 + r) * Kd) * 2 + colb;
    const char* Bb = (const char*)B + ((unsigned long)(n0 + wave * 32 + r) * Kd) * 2 + colb;
    const unsigned long rstep = (unsigned long)Kd * 32;   // 16 rows * Kd * 2B
    unsigned short* la = Asl + wave * 32 * 32;            // wave-uniform LDS bases
    unsigned short* lb = Bsl + wave * 32 * 32;

    f32x4 acc[4][4] = {};

    for (int kk = 0; kk < Kd; kk += 32) {
        __syncthreads();                       // WAR: prev frag reads done
        gload16(Ab, la);
        gload16(Ab + rstep, la + 16 * 32);
        gload16(Bb, lb);
        gload16(Bb + rstep, lb + 16 * 32);
        Ab += 64; Bb += 64;
        __syncthreads();                       // drains vmcnt -> data visible
        bf16x8 af[4], bfr[4];
        #pragma unroll
        for (int i = 0; i < 4; ++i)
            af[i] = *(const bf16x8*)(Asl + (wm + i * 16 + l16) * 32 + quad * 8);
        #pragma unroll
        for (int j = 0; j < 4; ++j)
            bfr[j] = *(const bf16x8*)(Bsl + (wn + j * 16 + l16) * 32 + quad * 8);
        #pragma unroll
        for (int i = 0; i < 4; ++i)
            #pragma unroll
            for (int j = 0; j < 4; ++j)
                acc[i][j] = __builtin_amdgcn_mfma_f32_16x16x32_bf16(af[i], bfr[j], acc[i][j], 0, 0, 0);
    }

    #pragma unroll
    for (int i = 0; i < 4; ++i) {
        const int ob = m0 + wm + i * 16 + quad * 4;
        #pragma unroll
        for (int rr = 0; rr < 4; ++rr) {
            const int o = ob + rr;
            if (o >= Mvalid) continue;
            const float bv = (MODE == 1) ? bias[o] : 0.f;
            #pragma unroll
            for (int j = 0; j < 4; ++j) {
                const int n = n0 + wn + j * 16 + l16;
                const unsigned long ci = (unsigned long)o * NFULL + n;
                if (MODE == 0) {
                    ((unsigned short*)Cv)[ci] = f2bf(acc[i][j][rr]);
                } else if (MODE == 1) {
                    ((float*)Cv)[ci] = acc[i][j][rr] + bv;
                } else {
                    float* pc = (float*)Cv + ci;
                    *pc += acc[i][j][rr];
                }
            }
        }
    }
}

extern "C" void kernel_launch(void* const* d_in, const int* in_sizes, int n_in,
                              void* d_out, int out_size, void* d_ws, size_t ws_size,
                              hipStream_t stream) {
    const float* x      = (const float*)d_in[0];
    const float* w_off  = (const float*)d_in[1];
    const float* w_def  = (const float*)d_in[2];
    const float* w_temp = (const float*)d_in[3];
    const float* b_temp = (const float*)d_in[4];
    float* out = (float*)d_out;

    // workspace: big (117,964,800 B) | off_buf bf16 (3,686,400 B) | wb (3,538,944 B)
    unsigned short* big  = (unsigned short*)d_ws;
    unsigned short* offb = (unsigned short*)((char*)d_ws + 117964800ul);
    unsigned short* wb   = (unsigned short*)((char*)d_ws + 121651200ul);

    // Phase A: offset conv (M=200 padded to 256)
    cast5_k<<<6400, 256, 0, stream>>>(w_off, wb, OFFC);
    im2col5_k<<<dim3(36, T), 256, 0, stream>>>(x, big);
    gemm_k<0><<<dim3(72, 2), 256, 0, stream>>>(wb, big, offb, nullptr, CK5, OFFC);

    // Phase B: deformable conv (bias folded here)
    sample_k<<<dim3(36, T), 256, 0, stream>>>(x, offb, big);
    cast5_k<<<6400, 256, 0, stream>>>(w_def, wb, C);
    gemm_k<1><<<dim3(72, 2), 256, 0, stream>>>(wb, big, out, b_temp, CK5, C);

    // Phase C: temporal 3x3x3 conv as 3 accumulating GEMMs over kt
    im2col9_k<<<dim3(36, T), 256, 0, stream>>>(x, big);
    cast_temp_k<<<6912, 256, 0, stream>>>(w_temp, wb);
    // kt=0: out t=1..3 <- x t=0..2
    gemm_k<2><<<dim3(54, 2), 256, 0, stream>>>(wb, big, (void*)(out + 2304), nullptr, CK9, C);
    // kt=1: out t=0..3 <- x t=0..3
    gemm_k<2><<<dim3(72, 2), 256, 0, stream>>>(wb + 256 * 2304, big, (void*)out, nullptr, CK9, C);
    // kt=2: out t=0..2 <- x t=1..3
    gemm_k<2><<<dim3(54, 2), 256, 0, stream>>>(wb + 2 * 256 * 2304,
                                               big + (unsigned long)2304 * 2304,
                                               (void*)out, nullptr, CK9, C);
}

// Round 3
// 595.177 us; speedup vs baseline: 11.9536x; 1.9223x over previous
//
#include <hip/hip_runtime.h>

#define T    4
#define C    256
#define H    48
#define W    48
#define HW   2304
#define DG   4
#define OFFC 200
#define CK5  6400      // deform/offset GEMM K, (q,c) c-inner
#define CK9  2304      // temporal per-tap K, (j,c) c-inner
#define NFULL 9216     // T*HW

typedef __attribute__((ext_vector_type(8))) short bf16x8;
typedef __attribute__((ext_vector_type(4))) float f32x4;

__device__ __forceinline__ unsigned short f2bf(float f) {
    unsigned int u = __float_as_uint(f);
    return (unsigned short)((u + 0x7FFFu + ((u >> 16) & 1u)) >> 16);
}
__device__ __forceinline__ float bf2f(unsigned short u) {
    return __uint_as_float(((unsigned int)u) << 16);
}
__device__ __forceinline__ float bflo(unsigned int v) { return __uint_as_float(v << 16); }
__device__ __forceinline__ float bfhi(unsigned int v) { return __uint_as_float(v & 0xFFFF0000u); }
__device__ __forceinline__ void gload16(const void* g, void* l) {
    __builtin_amdgcn_global_load_lds(
        (const __attribute__((address_space(1))) unsigned int*)g,
        (__attribute__((address_space(3))) unsigned int*)l, 16, 0, 0);
}

// ---------------------------------------------------------------------------
// Weight casts (fp32 -> bf16, K-major (q,c) c-inner, parametrized output ld).
// ---------------------------------------------------------------------------
__global__ __launch_bounds__(256) void cast5_k(const float* __restrict__ w,
                                               unsigned short* __restrict__ a,
                                               int mvalid, int ldOut) {
    const int idx = blockIdx.x * 256 + threadIdx.x;      // < 256*6400
    const int c = idx & 255, rest = idx >> 8;
    const int q = rest % 25, o = rest / 25;
    a[(long)o * ldOut + q * 256 + c] =
        (o < mvalid) ? f2bf(w[((long)o * 256 + c) * 25 + q]) : (unsigned short)0;
}
__global__ __launch_bounds__(256) void cast_temp_k(const float* __restrict__ w,
                                                   unsigned short* __restrict__ a,
                                                   int ldOut, int colOff, long ktStride) {
    const int idx = blockIdx.x * 256 + threadIdx.x;      // < 3*256*2304
    const int c = idx & 255, rest = idx >> 8;
    const int j = rest % 9, oo = rest / 9;
    const int o = oo & 255, kt = oo >> 8;
    a[(long)kt * ktStride + (long)o * ldOut + colOff + j * 256 + c] =
        f2bf(w[((long)o * 256 + c) * 27 + kt * 9 + j]);
}

// ---------------------------------------------------------------------------
// x[c][t][p] fp32 -> xt[t][p][c] bf16 via LDS transpose. grid (36, 4 ct, T)
// ---------------------------------------------------------------------------
__global__ __launch_bounds__(256) void xt_k(const float* __restrict__ x,
                                            unsigned short* __restrict__ xt) {
    __shared__ float tile[64][65];
    const int p0 = blockIdx.x * 64, c0 = blockIdx.y * 64, t = blockIdx.z;
    const int px = threadIdx.x & 63, sub = threadIdx.x >> 6;
    for (int cl = sub; cl < 64; cl += 4)
        tile[px][cl] = x[((long)(c0 + cl) * T + t) * HW + p0 + px];
    __syncthreads();
    const int seg = sub * 16;
    unsigned int pk[8];
    #pragma unroll
    for (int d = 0; d < 8; ++d)
        pk[d] = (unsigned int)f2bf(tile[px][seg + d * 2]) |
                ((unsigned int)f2bf(tile[px][seg + d * 2 + 1]) << 16);
    unsigned short* orow = xt + ((long)t * HW + p0 + px) * 256 + c0 + seg;
    *(uint4*)(orow + 0) = make_uint4(pk[0], pk[1], pk[2], pk[3]);
    *(uint4*)(orow + 8) = make_uint4(pk[4], pk[5], pk[6], pk[7]);
}

// ---------------------------------------------------------------------------
// im2col 5x5 pad2: big[(t,p)][q*256+c].  grid (36, T, 4)
// ---------------------------------------------------------------------------
__global__ __launch_bounds__(256) void im2col5_k(const float* __restrict__ x,
                                                 unsigned short* __restrict__ big) {
    const int t = blockIdx.y, p0 = blockIdx.x * 64, z = blockIdx.z;
    const int px = threadIdx.x & 63, sub = threadIdx.x >> 6;
    const int p = p0 + px, h = p / 48, w = p - h * 48;
    unsigned short* orow = big + ((long)t * HW + p) * CK5;
    for (int q = 0; q < 25; ++q) {
        const int qy = q / 5, qx = q - qy * 5;
        const int y = h + qy - 2, xx = w + qx - 2;
        const bool valid = (y >= 0) & (y < 48) & (xx >= 0) & (xx < 48);
        const int idx = valid ? (y * 48 + xx) : 0;
        for (int s = 0; s < 2; ++s) {
            const int cgrp = sub + (z * 2 + s) * 4;
            unsigned int pk[4];
            #pragma unroll
            for (int d = 0; d < 4; ++d) {
                const int cc = cgrp * 8 + d * 2;
                const float v0 = valid ? x[((long)cc * T + t) * HW + idx] : 0.f;
                const float v1 = valid ? x[((long)(cc + 1) * T + t) * HW + idx] : 0.f;
                pk[d] = (unsigned int)f2bf(v0) | ((unsigned int)f2bf(v1) << 16);
            }
            *(uint4*)(orow + q * 256 + cgrp * 8) = make_uint4(pk[0], pk[1], pk[2], pk[3]);
        }
    }
}

// im2col 3x3 pad1: dst[(t,p)][j*256+c].  grid (36, T, 4)
__global__ __launch_bounds__(256) void im2col9_k(const float* __restrict__ x,
                                                 unsigned short* __restrict__ dst) {
    const int t = blockIdx.y, p0 = blockIdx.x * 64, z = blockIdx.z;
    const int px = threadIdx.x & 63, sub = threadIdx.x >> 6;
    const int p = p0 + px, h = p / 48, w = p - h * 48;
    unsigned short* orow = dst + ((long)t * HW + p) * CK9;
    for (int q = 0; q < 9; ++q) {
        const int qy = q / 3, qx = q - qy * 3;
        const int y = h + qy - 1, xx = w + qx - 1;
        const bool valid = (y >= 0) & (y < 48) & (xx >= 0) & (xx < 48);
        const int idx = valid ? (y * 48 + xx) : 0;
        for (int s = 0; s < 2; ++s) {
            const int cgrp = sub + (z * 2 + s) * 4;
            unsigned int pk[4];
            #pragma unroll
            for (int d = 0; d < 4; ++d) {
                const int cc = cgrp * 8 + d * 2;
                const float v0 = valid ? x[((long)cc * T + t) * HW + idx] : 0.f;
                const float v1 = valid ? x[((long)(cc + 1) * T + t) * HW + idx] : 0.f;
                pk[d] = (unsigned int)f2bf(v0) | ((unsigned int)f2bf(v1) << 16);
            }
            *(uint4*)(orow + q * 256 + cgrp * 8) = make_uint4(pk[0], pk[1], pk[2], pk[3]);
        }
    }
}

// ---------------------------------------------------------------------------
// Shared position precompute for samplers (per-block: 64 px, one t, one g).
// ---------------------------------------------------------------------------
__device__ __forceinline__ void samp_positions(const unsigned short* __restrict__ off,
                                               int t, int g, int p0,
                                               float2* pw, short2* pi) {
    for (int e = threadIdx.x; e < 1600; e += 256) {   // e = k*64+px
        const int px = e & 63, k = e >> 6;
        const int p = p0 + px, h = p / 48, w = p - h * 48;
        const float dy = bf2f(off[(long)(g * 50 + 2 * k) * NFULL + t * HW + p]);
        const float dx = bf2f(off[(long)(g * 50 + 2 * k + 1) * NFULL + t * HW + p]);
        const int ky = k / 5, kx = k - ky * 5;
        const float sy = (float)(h + ky - 2) + dy;
        const float sx = (float)(w + kx - 2) + dx;
        const float y0f = floorf(sy), x0f = floorf(sx);
        pw[e] = make_float2(sy - y0f, sx - x0f);
        pi[e] = make_short2((short)y0f, (short)x0f);
    }
}
__device__ __forceinline__ void corner_setup(float2 wyx, short2 yx,
                                             float& w00, float& w01, float& w10, float& w11,
                                             int& i00, int& i01, int& i10, int& i11) {
    const int y0 = yx.x, x0 = yx.y, y1 = y0 + 1, x1 = x0 + 1;
    const float wy = wyx.x, wx = wyx.y;
    w00 = (1.f - wy) * (1.f - wx);
    w01 = (1.f - wy) * wx;
    w10 = wy * (1.f - wx);
    w11 = wy * wx;
    const bool vy0 = (y0 >= 0) & (y0 < 48), vy1 = (y1 >= 0) & (y1 < 48);
    const bool vx0 = (x0 >= 0) & (x0 < 48), vx1 = (x1 >= 0) & (x1 < 48);
    if (!(vy0 & vx0)) w00 = 0.f;
    if (!(vy0 & vx1)) w01 = 0.f;
    if (!(vy1 & vx0)) w10 = 0.f;
    if (!(vy1 & vx1)) w11 = 0.f;
    const int yc0 = min(max(y0, 0), 47), yc1 = min(max(y1, 0), 47);
    const int xc0 = min(max(x0, 0), 47), xc1 = min(max(x1, 0), 47);
    i00 = yc0 * 48 + xc0; i01 = yc0 * 48 + xc1;
    i10 = yc1 * 48 + xc0; i11 = yc1 * 48 + xc1;
}

// Sampler (primary): reads xt[t][p][c] bf16, vectorized over c. grid (36,T,DG)
__global__ __launch_bounds__(256) void sample_xt_k(const unsigned short* __restrict__ xt,
                                                   const unsigned short* __restrict__ off,
                                                   unsigned short* __restrict__ big) {
    __shared__ float2 pw[1600];
    __shared__ short2 pi[1600];
    const int p0 = blockIdx.x * 64, t = blockIdx.y, g = blockIdx.z;
    samp_positions(off, t, g, p0, pw, pi);
    __syncthreads();

    const int px = threadIdx.x & 63, ks = threadIdx.x >> 6;
    const int p = p0 + px;
    const unsigned short* xtb = xt + (long)t * HW * 256 + g * 64;
    unsigned short* orow = big + ((long)t * HW + p) * CK5 + g * 64;
    for (int k = ks; k < 25; k += 4) {
        const int e = k * 64 + px;
        float w00, w01, w10, w11; int i00, i01, i10, i11;
        corner_setup(pw[e], pi[e], w00, w01, w10, w11, i00, i01, i10, i11);
        const unsigned short* r00 = xtb + i00 * 256;
        const unsigned short* r01 = xtb + i01 * 256;
        const unsigned short* r10 = xtb + i10 * 256;
        const unsigned short* r11 = xtb + i11 * 256;
        unsigned short* ow = orow + k * 256;
        #pragma unroll
        for (int d = 0; d < 8; ++d) {
            const uint4 u00 = *(const uint4*)(r00 + d * 8);
            const uint4 u01 = *(const uint4*)(r01 + d * 8);
            const uint4 u10 = *(const uint4*)(r10 + d * 8);
            const uint4 u11 = *(const uint4*)(r11 + d * 8);
            unsigned int pk[4];
            #pragma unroll
            for (int q = 0; q < 4; ++q) {
                const unsigned int a = ((const unsigned int*)&u00)[q];
                const unsigned int b = ((const unsigned int*)&u01)[q];
                const unsigned int cq = ((const unsigned int*)&u10)[q];
                const unsigned int dq = ((const unsigned int*)&u11)[q];
                const float rl = w00 * bflo(a) + w01 * bflo(b) + w10 * bflo(cq) + w11 * bflo(dq);
                const float rh = w00 * bfhi(a) + w01 * bfhi(b) + w10 * bfhi(cq) + w11 * bfhi(dq);
                pk[q] = (unsigned int)f2bf(rl) | ((unsigned int)f2bf(rh) << 16);
            }
            *(uint4*)(ow + d * 8) = make_uint4(pk[0], pk[1], pk[2], pk[3]);
        }
    }
}

// Sampler (fallback, no xt buffer): fp32 gathers from x. grid (36,T,DG)
__global__ __launch_bounds__(256) void sample_direct_k(const float* __restrict__ x,
                                                       const unsigned short* __restrict__ off,
                                                       unsigned short* __restrict__ big) {
    __shared__ float2 pw[1600];
    __shared__ short2 pi[1600];
    const int p0 = blockIdx.x * 64, t = blockIdx.y, g = blockIdx.z;
    samp_positions(off, t, g, p0, pw, pi);
    __syncthreads();

    const int px = threadIdx.x & 63, cs = threadIdx.x >> 6;
    const int p = p0 + px;
    unsigned short* orow = big + ((long)t * HW + p) * CK5 + g * 64;
    for (int k = 0; k < 25; ++k) {
        const int e = k * 64 + px;
        float w00, w01, w10, w11; int i00, i01, i10, i11;
        corner_setup(pw[e], pi[e], w00, w01, w10, w11, i00, i01, i10, i11);
        for (int oct = cs; oct < 8; oct += 4) {
            unsigned int pk[4];
            #pragma unroll
            for (int d = 0; d < 4; ++d) {
                const int cc = g * 64 + oct * 8 + d * 2;
                const float* x0p = x + ((long)cc * T + t) * HW;
                const float* x1p = x0p + (long)T * HW;
                const float v0 = w00 * x0p[i00] + w01 * x0p[i01] + w10 * x0p[i10] + w11 * x0p[i11];
                const float v1 = w00 * x1p[i00] + w01 * x1p[i01] + w10 * x1p[i10] + w11 * x1p[i11];
                pk[d] = (unsigned int)f2bf(v0) | ((unsigned int)f2bf(v1) << 16);
            }
            *(uint4*)(orow + k * 256 + oct * 8) = make_uint4(pk[0], pk[1], pk[2], pk[3]);
        }
    }
}

// ---------------------------------------------------------------------------
// MFMA GEMM, BM=128 BN=64 BK=32, phased K:
//   P1: K=6400 over B1 (ld 6400);  PT: 3 temporal taps over B9 (ld 2304, t-shifted)
// MODE 0: store bf16; 1: store fp32 + bias; 2: fp32 +=.  grid (144, 2).
// ---------------------------------------------------------------------------
template <int MODE, bool P1, bool PT>
__global__ __launch_bounds__(256) void gemm_k(const unsigned short* __restrict__ A1, int ldA1,
                                              const unsigned short* __restrict__ AT, int ldAT,
                                              long ktStrideA,
                                              const unsigned short* __restrict__ B1,
                                              const unsigned short* __restrict__ B9,
                                              void* __restrict__ Cv,
                                              const float* __restrict__ bias, int Mvalid) {
    __shared__ unsigned short Asl[128 * 32];
    __shared__ unsigned short Bsl[64 * 32];
    const int tid = threadIdx.x;
    const int wave = tid >> 6, lane = tid & 63;
    const int quad = lane >> 4, l16 = lane & 15;
    const int n0 = blockIdx.x * 64, m0 = blockIdx.y * 128;
    const int t = n0 / HW, p0 = n0 - t * HW;
    const int wm = (wave & 1) * 64, wn = (wave >> 1) * 32;
    const int r = lane >> 2, cb = (lane & 3) * 8;
    unsigned short* la = Asl + wave * 1024;
    unsigned short* lb = Bsl + wave * 512;

    f32x4 acc[4][2] = {};

    auto run = [&](const unsigned short* Ab, int ldA, const unsigned short* Bb, int ldB,
                   int ksteps) {
        const char* Ap = (const char*)(Ab + (long)(m0 + wave * 32 + r) * ldA + cb);
        const char* Bp = (const char*)(Bb + (long)(wave * 16 + r) * ldB + cb);
        const long arstep = (long)ldA * 32;   // bytes for 16 rows
        for (int s = 0; s < ksteps; ++s) {
            __syncthreads();
            gload16(Ap, la);
            gload16(Ap + arstep, la + 512);
            gload16(Bp, lb);
            Ap += 64; Bp += 64;
            __syncthreads();
            bf16x8 af[4], bfr[2];
            #pragma unroll
            for (int i = 0; i < 4; ++i)
                af[i] = *(const bf16x8*)(Asl + (wm + i * 16 + l16) * 32 + quad * 8);
            #pragma unroll
            for (int j = 0; j < 2; ++j)
                bfr[j] = *(const bf16x8*)(Bsl + (wn + j * 16 + l16) * 32 + quad * 8);
            #pragma unroll
            for (int i = 0; i < 4; ++i)
                #pragma unroll
                for (int j = 0; j < 2; ++j)
                    acc[i][j] = __builtin_amdgcn_mfma_f32_16x16x32_bf16(af[i], bfr[j], acc[i][j], 0, 0, 0);
        }
    };

    if constexpr (P1) run(A1, ldA1, B1 + (long)n0 * CK5, CK5, 200);
    if constexpr (PT) {
        #pragma unroll
        for (int kt = 0; kt < 3; ++kt) {
            const int tsrc = t + kt - 1;
            if (tsrc >= 0 && tsrc < T)
                run(AT + (long)kt * ktStrideA, ldAT,
                    B9 + ((long)tsrc * HW + p0) * CK9, CK9, 72);
        }
    }

    #pragma unroll
    for (int i = 0; i < 4; ++i) {
        const int ob = m0 + wm + i * 16 + quad * 4;
        #pragma unroll
        for (int rr = 0; rr < 4; ++rr) {
            const int o = ob + rr;
            if (o >= Mvalid) continue;
            const float bv = (MODE == 1) ? bias[o] : 0.f;
            #pragma unroll
            for (int j = 0; j < 2; ++j) {
                const int n = n0 + wn + j * 16 + l16;
                const long ci = (long)o * NFULL + n;
                if (MODE == 0)      ((unsigned short*)Cv)[ci] = f2bf(acc[i][j][rr]);
                else if (MODE == 1) ((float*)Cv)[ci] = acc[i][j][rr] + bv;
                else                ((float*)Cv)[ci] += acc[i][j][rr];
            }
        }
    }
}

extern "C" void kernel_launch(void* const* d_in, const int* in_sizes, int n_in,
                              void* d_out, int out_size, void* d_ws, size_t ws_size,
                              hipStream_t stream) {
    const float* x      = (const float*)d_in[0];
    const float* w_off  = (const float*)d_in[1];
    const float* w_def  = (const float*)d_in[2];
    const float* w_temp = (const float*)d_in[3];
    const float* b_temp = (const float*)d_in[4];
    float* out = (float*)d_out;

    const size_t BIG  = 117964800ul;   // 9216 x 6400 bf16 (im2col5 then samp)
    const size_t IM9  = 42467328ul;    // 9216 x 2304 bf16
    const size_t OFFB = 3686400ul;     // 200 x 9216 bf16

    if (ws_size >= 170934272ul) {
        // ---- primary: xt sampler + fused deform+temporal GEMM ----
        unsigned short* big  = (unsigned short*)d_ws;
        unsigned short* im9  = (unsigned short*)((char*)d_ws + BIG);
        unsigned short* offb = (unsigned short*)((char*)d_ws + BIG + IM9);
        unsigned short* R    = (unsigned short*)((char*)d_ws + BIG + IM9 + OFFB);
        unsigned short* wbo  = R;                         // 256x6400  (3,276,800 B)
        unsigned short* xt   = R;                         // 9216x256  (4,718,592 B)
        unsigned short* wb2  = R;                         // 256x13312 (6,815,744 B)

        cast5_k<<<6400, 256, 0, stream>>>(w_off, wbo, OFFC, CK5);
        im2col5_k<<<dim3(36, T, 4), 256, 0, stream>>>(x, big);
        gemm_k<0, true, false><<<dim3(144, 2), 256, 0, stream>>>(
            wbo, CK5, nullptr, 0, 0, big, nullptr, offb, nullptr, OFFC);
        xt_k<<<dim3(36, 4, T), 256, 0, stream>>>(x, xt);
        sample_xt_k<<<dim3(36, T, DG), 256, 0, stream>>>(xt, offb, big);
        cast5_k<<<6400, 256, 0, stream>>>(w_def, wb2, C, 13312);
        cast_temp_k<<<6912, 256, 0, stream>>>(w_temp, wb2, 13312, CK5, CK9);
        im2col9_k<<<dim3(36, T, 4), 256, 0, stream>>>(x, im9);
        gemm_k<1, true, true><<<dim3(144, 2), 256, 0, stream>>>(
            wb2, 13312, wb2 + CK5, 13312, CK9, big, im9, out, b_temp, C);
    } else {
        // ---- fallback: proven 125.19 MB footprint ----
        unsigned short* big  = (unsigned short*)d_ws;
        unsigned short* offb = (unsigned short*)((char*)d_ws + BIG);
        unsigned short* R    = (unsigned short*)((char*)d_ws + BIG + OFFB);
        // R reused: wbo (3,276,800) -> wbd (3,276,800) -> wbT (3,538,944)

        cast5_k<<<6400, 256, 0, stream>>>(w_off, R, OFFC, CK5);
        im2col5_k<<<dim3(36, T, 4), 256, 0, stream>>>(x, big);
        gemm_k<0, true, false><<<dim3(144, 2), 256, 0, stream>>>(
            R, CK5, nullptr, 0, 0, big, nullptr, offb, nullptr, OFFC);
        sample_direct_k<<<dim3(36, T, DG), 256, 0, stream>>>(x, offb, big);
        cast5_k<<<6400, 256, 0, stream>>>(w_def, R, C, CK5);
        gemm_k<1, true, false><<<dim3(144, 2), 256, 0, stream>>>(
            R, CK5, nullptr, 0, 0, big, nullptr, out, b_temp, C);
        im2col9_k<<<dim3(36, T, 4), 256, 0, stream>>>(x, big);   // big reused as im9
        cast_temp_k<<<6912, 256, 0, stream>>>(w_temp, R, CK9, 0, (long)C * CK9);
        gemm_k<2, false, true><<<dim3(144, 2), 256, 0, stream>>>(
            nullptr, 0, R, CK9, (long)C * CK9, nullptr, big, out, nullptr, C);
    }
}

// Round 4
// 517.463 us; speedup vs baseline: 13.7489x; 1.1502x over previous
//
#include <hip/hip_runtime.h>

#define T    4
#define C    256
#define H    48
#define W    48
#define HW   2304
#define DG   4
#define OFFC 200
#define CK5  6400      // deform/offset GEMM K, (q,c) c-inner
#define CK9  2304      // temporal per-tap K, (j,c) c-inner
#define NFULL 9216     // T*HW

typedef __attribute__((ext_vector_type(8))) short bf16x8;
typedef __attribute__((ext_vector_type(4))) float f32x4;

__device__ __forceinline__ unsigned short f2bf(float f) {
    unsigned int u = __float_as_uint(f);
    return (unsigned short)((u + 0x7FFFu + ((u >> 16) & 1u)) >> 16);
}
__device__ __forceinline__ float bflo(unsigned int v) { return __uint_as_float(v << 16); }
__device__ __forceinline__ float bfhi(unsigned int v) { return __uint_as_float(v & 0xFFFF0000u); }
__device__ __forceinline__ void gload16(const void* g, void* l) {
    __builtin_amdgcn_global_load_lds(
        (const __attribute__((address_space(1))) unsigned int*)g,
        (__attribute__((address_space(3))) unsigned int*)l, 16, 0, 0);
}

// ---------------------------------------------------------------------------
// Weight casts (fp32 -> bf16, K-major, c inner).
// ---------------------------------------------------------------------------
__global__ __launch_bounds__(256) void cast5_k(const float* __restrict__ w,
                                               unsigned short* __restrict__ a, int mvalid) {
    const int idx = blockIdx.x * 256 + threadIdx.x;      // < 256*6400
    const int c = idx & 255, rest = idx >> 8;
    const int q = rest % 25, o = rest / 25;
    a[(long)o * CK5 + q * 256 + c] =
        (o < mvalid) ? f2bf(w[((long)o * 256 + c) * 25 + q]) : (unsigned short)0;
}
// wbT[kt][o][(j,c)], j = kh*3+kw
__global__ __launch_bounds__(256) void cast_temp_k(const float* __restrict__ w,
                                                   unsigned short* __restrict__ a) {
    const int idx = blockIdx.x * 256 + threadIdx.x;      // < 3*256*2304
    const int c = idx & 255, rest = idx >> 8;
    const int j = rest % 9, oo = rest / 9;
    const int o = oo & 255, kt = oo >> 8;
    a[(long)kt * (256 * CK9) + (long)o * CK9 + j * 256 + c] =
        f2bf(w[((long)o * 256 + c) * 27 + kt * 9 + j]);
}

// ---------------------------------------------------------------------------
// Fills: out[o][n] = bias[o];  zero fp32 buffer.  (float4 per thread)
// ---------------------------------------------------------------------------
__global__ __launch_bounds__(256) void fill_bias_k(float* __restrict__ out,
                                                   const float* __restrict__ bias) {
    const long i4 = (long)blockIdx.x * 256 + threadIdx.x;   // < 589824
    const float b = bias[(int)(i4 / (NFULL / 4))];
    ((float4*)out)[i4] = make_float4(b, b, b, b);
}
__global__ __launch_bounds__(256) void zero_k(float* __restrict__ p) {
    ((float4*)p)[(long)blockIdx.x * 256 + threadIdx.x] = make_float4(0.f, 0.f, 0.f, 0.f);
}

// ---------------------------------------------------------------------------
// x[c][t][p] fp32 -> xt[t][p][c] bf16 via LDS transpose. grid (36, 4 ct, T)
// ---------------------------------------------------------------------------
__global__ __launch_bounds__(256) void xt_k(const float* __restrict__ x,
                                            unsigned short* __restrict__ xt) {
    __shared__ float tile[64][65];
    const int p0 = blockIdx.x * 64, c0 = blockIdx.y * 64, t = blockIdx.z;
    const int px = threadIdx.x & 63, sub = threadIdx.x >> 6;
    for (int cl = sub; cl < 64; cl += 4)
        tile[px][cl] = x[((long)(c0 + cl) * T + t) * HW + p0 + px];
    __syncthreads();
    const int seg = sub * 16;
    unsigned int pk[8];
    #pragma unroll
    for (int d = 0; d < 8; ++d)
        pk[d] = (unsigned int)f2bf(tile[px][seg + d * 2]) |
                ((unsigned int)f2bf(tile[px][seg + d * 2 + 1]) << 16);
    unsigned short* orow = xt + ((long)t * HW + p0 + px) * 256 + c0 + seg;
    *(uint4*)(orow + 0) = make_uint4(pk[0], pk[1], pk[2], pk[3]);
    *(uint4*)(orow + 8) = make_uint4(pk[4], pk[5], pk[6], pk[7]);
}

// ---------------------------------------------------------------------------
// im2col 5x5 pad2: big[(t,p)][q*256+c].  grid (36, T, 4)
// ---------------------------------------------------------------------------
__global__ __launch_bounds__(256) void im2col5_k(const float* __restrict__ x,
                                                 unsigned short* __restrict__ big) {
    const int t = blockIdx.y, p0 = blockIdx.x * 64, z = blockIdx.z;
    const int px = threadIdx.x & 63, sub = threadIdx.x >> 6;
    const int p = p0 + px, h = p / 48, w = p - h * 48;
    unsigned short* orow = big + ((long)t * HW + p) * CK5;
    for (int q = 0; q < 25; ++q) {
        const int qy = q / 5, qx = q - qy * 5;
        const int y = h + qy - 2, xx = w + qx - 2;
        const bool valid = (y >= 0) & (y < 48) & (xx >= 0) & (xx < 48);
        const int idx = valid ? (y * 48 + xx) : 0;
        for (int s = 0; s < 2; ++s) {
            const int cgrp = sub + (z * 2 + s) * 4;
            unsigned int pk[4];
            #pragma unroll
            for (int d = 0; d < 4; ++d) {
                const int cc = cgrp * 8 + d * 2;
                const float v0 = valid ? x[((long)cc * T + t) * HW + idx] : 0.f;
                const float v1 = valid ? x[((long)(cc + 1) * T + t) * HW + idx] : 0.f;
                pk[d] = (unsigned int)f2bf(v0) | ((unsigned int)f2bf(v1) << 16);
            }
            *(uint4*)(orow + q * 256 + cgrp * 8) = make_uint4(pk[0], pk[1], pk[2], pk[3]);
        }
    }
}

// ---------------------------------------------------------------------------
// Sampler: positions from fp32 offsets, values from xt (bf16, c-vectorized).
// grid (36, T, DG)
// ---------------------------------------------------------------------------
__device__ __forceinline__ void corner_setup(float2 wyx, short2 yx,
                                             float& w00, float& w01, float& w10, float& w11,
                                             int& i00, int& i01, int& i10, int& i11) {
    const int y0 = yx.x, x0 = yx.y, y1 = y0 + 1, x1 = x0 + 1;
    const float wy = wyx.x, wx = wyx.y;
    w00 = (1.f - wy) * (1.f - wx);
    w01 = (1.f - wy) * wx;
    w10 = wy * (1.f - wx);
    w11 = wy * wx;
    const bool vy0 = (y0 >= 0) & (y0 < 48), vy1 = (y1 >= 0) & (y1 < 48);
    const bool vx0 = (x0 >= 0) & (x0 < 48), vx1 = (x1 >= 0) & (x1 < 48);
    if (!(vy0 & vx0)) w00 = 0.f;
    if (!(vy0 & vx1)) w01 = 0.f;
    if (!(vy1 & vx0)) w10 = 0.f;
    if (!(vy1 & vx1)) w11 = 0.f;
    const int yc0 = min(max(y0, 0), 47), yc1 = min(max(y1, 0), 47);
    const int xc0 = min(max(x0, 0), 47), xc1 = min(max(x1, 0), 47);
    i00 = yc0 * 48 + xc0; i01 = yc0 * 48 + xc1;
    i10 = yc1 * 48 + xc0; i11 = yc1 * 48 + xc1;
}

__global__ __launch_bounds__(256) void sample_xt_k(const unsigned short* __restrict__ xt,
                                                   const float* __restrict__ off32,
                                                   unsigned short* __restrict__ big) {
    __shared__ float2 pw[1600];
    __shared__ short2 pi[1600];
    const int p0 = blockIdx.x * 64, t = blockIdx.y, g = blockIdx.z;

    for (int e = threadIdx.x; e < 1600; e += 256) {   // e = k*64+px
        const int px = e & 63, k = e >> 6;
        const int p = p0 + px, h = p / 48, w = p - h * 48;
        const float dy = off32[(long)(g * 50 + 2 * k) * NFULL + t * HW + p];
        const float dx = off32[(long)(g * 50 + 2 * k + 1) * NFULL + t * HW + p];
        const int ky = k / 5, kx = k - ky * 5;
        const float sy = (float)(h + ky - 2) + dy;
        const float sx = (float)(w + kx - 2) + dx;
        const float y0f = floorf(sy), x0f = floorf(sx);
        pw[e] = make_float2(sy - y0f, sx - x0f);
        pi[e] = make_short2((short)y0f, (short)x0f);
    }
    __syncthreads();

    const int px = threadIdx.x & 63, ks = threadIdx.x >> 6;
    const int p = p0 + px;
    const unsigned short* xtb = xt + (long)t * HW * 256 + g * 64;
    unsigned short* orow = big + ((long)t * HW + p) * CK5 + g * 64;
    for (int k = ks; k < 25; k += 4) {
        const int e = k * 64 + px;
        float w00, w01, w10, w11; int i00, i01, i10, i11;
        corner_setup(pw[e], pi[e], w00, w01, w10, w11, i00, i01, i10, i11);
        const unsigned short* r00 = xtb + i00 * 256;
        const unsigned short* r01 = xtb + i01 * 256;
        const unsigned short* r10 = xtb + i10 * 256;
        const unsigned short* r11 = xtb + i11 * 256;
        unsigned short* ow = orow + k * 256;
        #pragma unroll
        for (int d = 0; d < 8; ++d) {
            const uint4 u00 = *(const uint4*)(r00 + d * 8);
            const uint4 u01 = *(const uint4*)(r01 + d * 8);
            const uint4 u10 = *(const uint4*)(r10 + d * 8);
            const uint4 u11 = *(const uint4*)(r11 + d * 8);
            unsigned int pk[4];
            #pragma unroll
            for (int q = 0; q < 4; ++q) {
                const unsigned int a  = ((const unsigned int*)&u00)[q];
                const unsigned int b  = ((const unsigned int*)&u01)[q];
                const unsigned int cq = ((const unsigned int*)&u10)[q];
                const unsigned int dq = ((const unsigned int*)&u11)[q];
                const float rl = w00 * bflo(a) + w01 * bflo(b) + w10 * bflo(cq) + w11 * bflo(dq);
                const float rh = w00 * bfhi(a) + w01 * bfhi(b) + w10 * bfhi(cq) + w11 * bfhi(dq);
                pk[q] = (unsigned int)f2bf(rl) | ((unsigned int)f2bf(rh) << 16);
            }
            *(uint4*)(ow + d * 8) = make_uint4(pk[0], pk[1], pk[2], pk[3]);
        }
    }
}

// ---------------------------------------------------------------------------
// Split-K MFMA GEMM: Cf[o][n] += A[o][k0..k0+kLen) * B[n][k0..)^T (atomic).
// BM=128 BN=64 BK=32; grid (144, 2, splits).
// ---------------------------------------------------------------------------
__global__ __launch_bounds__(256) void gemm_splitk_k(const unsigned short* __restrict__ A,
                                                     const unsigned short* __restrict__ B,
                                                     float* __restrict__ Cf,
                                                     int kLen, int Mvalid) {
    __shared__ unsigned short Asl[128 * 32];
    __shared__ unsigned short Bsl[64 * 32];
    const int tid = threadIdx.x;
    const int wave = tid >> 6, lane = tid & 63;
    const int quad = lane >> 4, l16 = lane & 15;
    const int n0 = blockIdx.x * 64, m0 = blockIdx.y * 128;
    const int k0 = blockIdx.z * kLen;
    const int wm = (wave & 1) * 64, wn = (wave >> 1) * 32;
    const int r = lane >> 2, cb = (lane & 3) * 16;   // bytes
    unsigned short* la = Asl + wave * 1024;
    unsigned short* lb = Bsl + wave * 512;

    f32x4 acc[4][2] = {};
    const char* Ap = (const char*)(A + (long)(m0 + wave * 32 + r) * CK5 + k0) + cb;
    const char* Bp = (const char*)(B + (long)(n0 + wave * 16 + r) * CK5 + k0) + cb;
    const long arstep = (long)CK5 * 32;              // 16 rows in bytes

    for (int s = 0; s < kLen / 32; ++s) {
        __syncthreads();
        gload16(Ap, la);
        gload16(Ap + arstep, la + 512);
        gload16(Bp, lb);
        Ap += 64; Bp += 64;
        __syncthreads();
        bf16x8 af[4], bfr[2];
        #pragma unroll
        for (int i = 0; i < 4; ++i)
            af[i] = *(const bf16x8*)(Asl + (wm + i * 16 + l16) * 32 + quad * 8);
        #pragma unroll
        for (int j = 0; j < 2; ++j)
            bfr[j] = *(const bf16x8*)(Bsl + (wn + j * 16 + l16) * 32 + quad * 8);
        #pragma unroll
        for (int i = 0; i < 4; ++i)
            #pragma unroll
            for (int j = 0; j < 2; ++j)
                acc[i][j] = __builtin_amdgcn_mfma_f32_16x16x32_bf16(af[i], bfr[j], acc[i][j], 0, 0, 0);
    }

    #pragma unroll
    for (int i = 0; i < 4; ++i) {
        #pragma unroll
        for (int rr = 0; rr < 4; ++rr) {
            const int o = m0 + wm + i * 16 + quad * 4 + rr;
            if (o >= Mvalid) continue;
            #pragma unroll
            for (int j = 0; j < 2; ++j) {
                const int n = n0 + wn + j * 16 + l16;
                unsafeAtomicAdd(Cf + (long)o * NFULL + n, acc[i][j][rr]);
            }
        }
    }
}

// ---------------------------------------------------------------------------
// Temporal GEMM: tap kt at output t reads im2col5 rows (t+kt-1, p), q-subset
// {6,7,8,11,12,13,16,17,18}.  grid (144, 2, 3).  Cf = out (atomic +=).
// ---------------------------------------------------------------------------
__global__ __launch_bounds__(256) void gemm_temp_k(const unsigned short* __restrict__ AT,
                                                   const unsigned short* __restrict__ B5,
                                                   float* __restrict__ Cf) {
    const int n0 = blockIdx.x * 64;
    const int kt = blockIdx.z;
    const int t = n0 / HW;
    const int tsrc = t + kt - 1;
    if (tsrc < 0 || tsrc >= T) return;

    __shared__ unsigned short Asl[128 * 32];
    __shared__ unsigned short Bsl[64 * 32];
    const int tid = threadIdx.x;
    const int wave = tid >> 6, lane = tid & 63;
    const int quad = lane >> 4, l16 = lane & 15;
    const int m0 = blockIdx.y * 128;
    const int p0 = n0 - t * HW;
    const int wm = (wave & 1) * 64, wn = (wave >> 1) * 32;
    const int r = lane >> 2, cb = (lane & 3) * 16;
    unsigned short* la = Asl + wave * 1024;
    unsigned short* lb = Bsl + wave * 512;

    const unsigned short* Ab = AT + (long)kt * (256 * CK9) + (long)(m0 + wave * 32 + r) * CK9;
    const unsigned short* Bb = B5 + (long)(tsrc * HW + p0 + wave * 16 + r) * CK5;
    const long arstep = (long)CK9 * 32;
    const int qmap[9] = {6, 7, 8, 11, 12, 13, 16, 17, 18};

    f32x4 acc[4][2] = {};
    for (int j = 0; j < 9; ++j) {
        const char* Ap = (const char*)(Ab + j * 256) + cb;
        const char* Bp = (const char*)(Bb + qmap[j] * 256) + cb;
        #pragma unroll
        for (int s = 0; s < 8; ++s) {
            __syncthreads();
            gload16(Ap, la);
            gload16(Ap + arstep, la + 512);
            gload16(Bp, lb);
            Ap += 64; Bp += 64;
            __syncthreads();
            bf16x8 af[4], bfr[2];
            #pragma unroll
            for (int i = 0; i < 4; ++i)
                af[i] = *(const bf16x8*)(Asl + (wm + i * 16 + l16) * 32 + quad * 8);
            #pragma unroll
            for (int jj = 0; jj < 2; ++jj)
                bfr[jj] = *(const bf16x8*)(Bsl + (wn + jj * 16 + l16) * 32 + quad * 8);
            #pragma unroll
            for (int i = 0; i < 4; ++i)
                #pragma unroll
                for (int jj = 0; jj < 2; ++jj)
                    acc[i][jj] = __builtin_amdgcn_mfma_f32_16x16x32_bf16(af[i], bfr[jj], acc[i][jj], 0, 0, 0);
        }
    }

    #pragma unroll
    for (int i = 0; i < 4; ++i) {
        #pragma unroll
        for (int rr = 0; rr < 4; ++rr) {
            const int o = m0 + wm + i * 16 + quad * 4 + rr;
            #pragma unroll
            for (int jj = 0; jj < 2; ++jj) {
                const int n = n0 + wn + jj * 16 + l16;
                unsafeAtomicAdd(Cf + (long)o * NFULL + n, acc[i][jj][rr]);
            }
        }
    }
}

extern "C" void kernel_launch(void* const* d_in, const int* in_sizes, int n_in,
                              void* d_out, int out_size, void* d_ws, size_t ws_size,
                              hipStream_t stream) {
    const float* x      = (const float*)d_in[0];
    const float* w_off  = (const float*)d_in[1];
    const float* w_def  = (const float*)d_in[2];
    const float* w_temp = (const float*)d_in[3];
    const float* b_temp = (const float*)d_in[4];
    float* out = (float*)d_out;

    // workspace (142.2 MB total; harness provides >= 170.9 MB, proven R3):
    unsigned short* big   = (unsigned short*)d_ws;                          // 117,964,800
    float*          offb  = (float*)((char*)d_ws + 117964800ul);            //   9,437,184
    unsigned short* xt    = (unsigned short*)((char*)d_ws + 127401984ul);   //   4,718,592
    unsigned short* wbo   = (unsigned short*)((char*)d_ws + 132120576ul);   //   3,276,800
    unsigned short* wbd   = (unsigned short*)((char*)d_ws + 135397376ul);   //   3,276,800
    unsigned short* wbT   = (unsigned short*)((char*)d_ws + 138674176ul);   //   3,538,944

    cast5_k<<<6400, 256, 0, stream>>>(w_off, wbo, OFFC);
    cast5_k<<<6400, 256, 0, stream>>>(w_def, wbd, C);
    cast_temp_k<<<6912, 256, 0, stream>>>(w_temp, wbT);
    im2col5_k<<<dim3(36, T, 4), 256, 0, stream>>>(x, big);
    xt_k<<<dim3(36, 4, T), 256, 0, stream>>>(x, xt);
    zero_k<<<2304, 256, 0, stream>>>(offb);
    fill_bias_k<<<2304, 256, 0, stream>>>(out, b_temp);

    // offset conv: K=6400 split 2 -> 576 blocks, atomic into offb (fp32)
    gemm_splitk_k<<<dim3(144, 2, 2), 256, 0, stream>>>(wbo, big, offb, 3200, OFFC);
    // temporal conv: 3 taps over im2col5 (must precede sampler's overwrite of big)
    gemm_temp_k<<<dim3(144, 2, 3), 256, 0, stream>>>(wbT, big, out);
    // deformable sampling (overwrites big) + deform GEMM, K split 2
    sample_xt_k<<<dim3(36, T, DG), 256, 0, stream>>>(xt, offb, big);
    gemm_splitk_k<<<dim3(144, 2, 2), 256, 0, stream>>>(wbd, big, out, 3200, C);
}

// Round 5
// 399.535 us; speedup vs baseline: 17.8070x; 1.2952x over previous
//
#include <hip/hip_runtime.h>

#define T    4
#define C    256
#define H    48
#define W    48
#define HW   2304
#define DG   4
#define OFFC 200
#define CK5  6400      // offset/deform K, (q,c) c-inner
#define CK9  2304      // temporal per-tap K, (j,c) c-inner
#define NFULL 9216     // T*HW

typedef __attribute__((ext_vector_type(8))) short bf16x8;
typedef __attribute__((ext_vector_type(4))) float f32x4;

__device__ __forceinline__ unsigned short f2bf(float f) {
    unsigned int u = __float_as_uint(f);
    return (unsigned short)((u + 0x7FFFu + ((u >> 16) & 1u)) >> 16);
}
__device__ __forceinline__ float bflo(unsigned int v) { return __uint_as_float(v << 16); }
__device__ __forceinline__ float bfhi(unsigned int v) { return __uint_as_float(v & 0xFFFF0000u); }
__device__ __forceinline__ void gload16(const void* g, void* l) {
    __builtin_amdgcn_global_load_lds(
        (const __attribute__((address_space(1))) unsigned int*)g,
        (__attribute__((address_space(3))) unsigned int*)l, 16, 0, 0);
}

// ---------------------------------------------------------------------------
// Weight casts (fp32 -> bf16, K-major, c inner).
// ---------------------------------------------------------------------------
__global__ __launch_bounds__(256) void cast5_k(const float* __restrict__ w,
                                               unsigned short* __restrict__ a, int mvalid) {
    const int idx = blockIdx.x * 256 + threadIdx.x;      // < 256*6400
    const int c = idx & 255, rest = idx >> 8;
    const int q = rest % 25, o = rest / 25;
    a[(long)o * CK5 + q * 256 + c] =
        (o < mvalid) ? f2bf(w[((long)o * 256 + c) * 25 + q]) : (unsigned short)0;
}
// wbT[kt][o][(j,c)], j = kh*3+kw
__global__ __launch_bounds__(256) void cast_temp_k(const float* __restrict__ w,
                                                   unsigned short* __restrict__ a) {
    const int idx = blockIdx.x * 256 + threadIdx.x;      // < 3*256*2304
    const int c = idx & 255, rest = idx >> 8;
    const int j = rest % 9, oo = rest / 9;
    const int o = oo & 255, kt = oo >> 8;
    a[(long)kt * (256 * CK9) + (long)o * CK9 + j * 256 + c] =
        f2bf(w[((long)o * 256 + c) * 27 + kt * 9 + j]);
}

// ---------------------------------------------------------------------------
// Fills.
// ---------------------------------------------------------------------------
__global__ __launch_bounds__(256) void fill_bias_k(float* __restrict__ out,
                                                   const float* __restrict__ bias) {
    const long i4 = (long)blockIdx.x * 256 + threadIdx.x;   // < 589824
    const float b = bias[(int)(i4 / (NFULL / 4))];
    ((float4*)out)[i4] = make_float4(b, b, b, b);
}
__global__ __launch_bounds__(256) void zero_k(float* __restrict__ p) {
    ((float4*)p)[(long)blockIdx.x * 256 + threadIdx.x] = make_float4(0.f, 0.f, 0.f, 0.f);
}

// ---------------------------------------------------------------------------
// x[c][t][p] fp32 -> xt[t][p][c] bf16 via LDS transpose. grid (36, 4 ct, T)
// ---------------------------------------------------------------------------
__global__ __launch_bounds__(256) void xt_k(const float* __restrict__ x,
                                            unsigned short* __restrict__ xt) {
    __shared__ float tile[64][65];
    const int p0 = blockIdx.x * 64, c0 = blockIdx.y * 64, t = blockIdx.z;
    const int px = threadIdx.x & 63, sub = threadIdx.x >> 6;
    for (int cl = sub; cl < 64; cl += 4)
        tile[px][cl] = x[((long)(c0 + cl) * T + t) * HW + p0 + px];
    __syncthreads();
    const int seg = sub * 16;
    unsigned int pk[8];
    #pragma unroll
    for (int d = 0; d < 8; ++d)
        pk[d] = (unsigned int)f2bf(tile[px][seg + d * 2]) |
                ((unsigned int)f2bf(tile[px][seg + d * 2 + 1]) << 16);
    unsigned short* orow = xt + ((long)t * HW + p0 + px) * 256 + c0 + seg;
    *(uint4*)(orow + 0) = make_uint4(pk[0], pk[1], pk[2], pk[3]);
    *(uint4*)(orow + 8) = make_uint4(pk[4], pk[5], pk[6], pk[7]);
}

// ---------------------------------------------------------------------------
// Shared MFMA tail: frag reads + 8 MFMAs (BM=128, BN=64, BK=32 layout).
// ---------------------------------------------------------------------------
__device__ __forceinline__ void mfma_step(const unsigned short* Asl,
                                          const unsigned short* Bsl,
                                          int wm, int wn, int quad, int l16,
                                          f32x4 acc[4][2]) {
    bf16x8 af[4], bfr[2];
    #pragma unroll
    for (int i = 0; i < 4; ++i)
        af[i] = *(const bf16x8*)(Asl + (wm + i * 16 + l16) * 32 + quad * 8);
    #pragma unroll
    for (int j = 0; j < 2; ++j)
        bfr[j] = *(const bf16x8*)(Bsl + (wn + j * 16 + l16) * 32 + quad * 8);
    #pragma unroll
    for (int i = 0; i < 4; ++i)
        #pragma unroll
        for (int j = 0; j < 2; ++j)
            acc[i][j] = __builtin_amdgcn_mfma_f32_16x16x32_bf16(af[i], bfr[j], acc[i][j], 0, 0, 0);
}
__device__ __forceinline__ void epilogue_atomic(float* Cf, int m0, int n0,
                                                int wm, int wn, int quad, int l16,
                                                int Mvalid, f32x4 acc[4][2]) {
    #pragma unroll
    for (int i = 0; i < 4; ++i)
        #pragma unroll
        for (int rr = 0; rr < 4; ++rr) {
            const int o = m0 + wm + i * 16 + quad * 4 + rr;
            if (o >= Mvalid) continue;
            #pragma unroll
            for (int j = 0; j < 2; ++j)
                unsafeAtomicAdd(Cf + (long)o * NFULL + n0 + wn + j * 16 + l16,
                                acc[i][j][rr]);
        }
}

// ---------------------------------------------------------------------------
// Implicit offset-conv GEMM: B[n][q*256+c] = xt[t][shift5(p,q)][c] (0 OOB).
// grid (144, 2, 2): split-K (3200 each), atomic into zeroed offb.
// ---------------------------------------------------------------------------
__global__ __launch_bounds__(256) void gemm_off_k(const unsigned short* __restrict__ A,
                                                  const unsigned short* __restrict__ xt,
                                                  float* __restrict__ Cf) {
    __shared__ unsigned short Asl[128 * 32];
    __shared__ unsigned short Bsl[64 * 32];
    const int tid = threadIdx.x;
    const int wave = tid >> 6, lane = tid & 63;
    const int quad = lane >> 4, l16 = lane & 15;
    const int n0 = blockIdx.x * 64, m0 = blockIdx.y * 128, k0 = blockIdx.z * 3200;
    const int t = n0 / HW, p0 = n0 - t * HW;
    const int wm = (wave & 1) * 64, wn = (wave >> 1) * 32;
    const int r = lane >> 2, cbl = (lane & 3) * 16;
    unsigned short* la = Asl + wave * 1024;

    const int px = tid >> 2, seg = tid & 3;
    const int p = p0 + px, h = p / 48, w = p - h * 48;
    const unsigned short* xtt = xt + (long)t * HW * 256 + seg * 8;

    const char* Ap = (const char*)(A + (long)(m0 + wave * 32 + r) * CK5 + k0) + cbl;
    const long arstep = (long)CK5 * 32;

    f32x4 acc[4][2] = {};
    for (int s = 0; s < 100; ++s) {
        const int kk = k0 + s * 32;
        const int q = kk >> 8, cb = kk & 255;
        const int qy = q / 5, qx = q - qy * 5;
        const int y = h + qy - 2, xx = w + qx - 2;
        const bool valid = (y >= 0) & (y < 48) & (xx >= 0) & (xx < 48);
        uint4 bv = make_uint4(0u, 0u, 0u, 0u);
        if (valid) bv = *(const uint4*)(xtt + (y * 48 + xx) * 256 + cb);
        __syncthreads();
        gload16(Ap, la);
        gload16(Ap + arstep, la + 512);
        Ap += 64;
        *(uint4*)(Bsl + px * 32 + seg * 8) = bv;
        __syncthreads();
        mfma_step(Asl, Bsl, wm, wn, quad, l16, acc);
    }
    epilogue_atomic(Cf, m0, n0, wm, wn, quad, l16, OFFC, acc);
}

// ---------------------------------------------------------------------------
// Implicit temporal GEMM: B[n][j*256+c] = xt[tsrc][shift3(p,j)][c] (0 OOB).
// grid (144, 2, 3): z = kt tap, atomic into bias-filled out.
// ---------------------------------------------------------------------------
__global__ __launch_bounds__(256) void gemm_temp_k(const unsigned short* __restrict__ AT,
                                                   const unsigned short* __restrict__ xt,
                                                   float* __restrict__ Cf) {
    const int n0 = blockIdx.x * 64, kt = blockIdx.z;
    const int t = n0 / HW;
    const int tsrc = t + kt - 1;
    if (tsrc < 0 || tsrc >= T) return;

    __shared__ unsigned short Asl[128 * 32];
    __shared__ unsigned short Bsl[64 * 32];
    const int tid = threadIdx.x;
    const int wave = tid >> 6, lane = tid & 63;
    const int quad = lane >> 4, l16 = lane & 15;
    const int m0 = blockIdx.y * 128, p0 = n0 - t * HW;
    const int wm = (wave & 1) * 64, wn = (wave >> 1) * 32;
    const int r = lane >> 2, cbl = (lane & 3) * 16;
    unsigned short* la = Asl + wave * 1024;

    const int px = tid >> 2, seg = tid & 3;
    const int p = p0 + px, h = p / 48, w = p - h * 48;
    const unsigned short* xtt = xt + (long)tsrc * HW * 256 + seg * 8;

    const char* Ap = (const char*)(AT + (long)kt * (256 * CK9)
                                   + (long)(m0 + wave * 32 + r) * CK9) + cbl;
    const long arstep = (long)CK9 * 32;

    f32x4 acc[4][2] = {};
    for (int s = 0; s < 72; ++s) {
        const int kk = s * 32;
        const int j = kk >> 8, cb = kk & 255;
        const int jy = j / 3, jx = j - jy * 3;
        const int y = h + jy - 1, xx = w + jx - 1;
        const bool valid = (y >= 0) & (y < 48) & (xx >= 0) & (xx < 48);
        uint4 bv = make_uint4(0u, 0u, 0u, 0u);
        if (valid) bv = *(const uint4*)(xtt + (y * 48 + xx) * 256 + cb);
        __syncthreads();
        gload16(Ap, la);
        gload16(Ap + arstep, la + 512);
        Ap += 64;
        *(uint4*)(Bsl + px * 32 + seg * 8) = bv;
        __syncthreads();
        mfma_step(Asl, Bsl, wm, wn, quad, l16, acc);
    }
    epilogue_atomic(Cf, m0, n0, wm, wn, quad, l16, C, acc);
}

// ---------------------------------------------------------------------------
// Implicit deformable GEMM: B[n][q*256+c] = bilinear(xt[t], pos(n,q,g(c))).
// Positions recomputed at each (q,g) boundary (every 64 k's).
// grid (144, 2, 2): split-K, atomic into out.
// ---------------------------------------------------------------------------
__global__ __launch_bounds__(256) void gemm_def_k(const unsigned short* __restrict__ A,
                                                  const unsigned short* __restrict__ xt,
                                                  const float* __restrict__ offb,
                                                  float* __restrict__ Cf) {
    __shared__ unsigned short Asl[128 * 32];
    __shared__ unsigned short Bsl[64 * 32];
    const int tid = threadIdx.x;
    const int wave = tid >> 6, lane = tid & 63;
    const int quad = lane >> 4, l16 = lane & 15;
    const int n0 = blockIdx.x * 64, m0 = blockIdx.y * 128, k0 = blockIdx.z * 3200;
    const int t = n0 / HW, p0 = n0 - t * HW;
    const int wm = (wave & 1) * 64, wn = (wave >> 1) * 32;
    const int r = lane >> 2, cbl = (lane & 3) * 16;
    unsigned short* la = Asl + wave * 1024;

    const int px = tid >> 2, seg = tid & 3;
    const int p = p0 + px, h = p / 48, w = p - h * 48;
    const int nabs = n0 + px;
    const unsigned short* xtt = xt + (long)t * HW * 256 + seg * 8;

    const char* Ap = (const char*)(A + (long)(m0 + wave * 32 + r) * CK5 + k0) + cbl;
    const long arstep = (long)CK5 * 32;

    float w00 = 0.f, w01 = 0.f, w10 = 0.f, w11 = 0.f;
    int i00 = 0, i01 = 0, i10 = 0, i11 = 0;

    f32x4 acc[4][2] = {};
    for (int s = 0; s < 100; ++s) {
        const int kk = k0 + s * 32;
        const int q = kk >> 8, cb = kk & 255;
        if ((kk & 63) == 0) {                      // new (q, g): refresh position
            const int g = cb >> 6;
            const float dy = offb[(long)(g * 50 + 2 * q) * NFULL + nabs];
            const float dx = offb[(long)(g * 50 + 2 * q + 1) * NFULL + nabs];
            const int qy = q / 5, qx = q - qy * 5;
            const float sy = (float)(h + qy - 2) + dy;
            const float sx = (float)(w + qx - 2) + dx;
            const float y0f = floorf(sy), x0f = floorf(sx);
            const float wy = sy - y0f, wx = sx - x0f;
            const int y0 = (int)y0f, x0 = (int)x0f;
            const int y1 = y0 + 1, x1 = x0 + 1;
            w00 = (1.f - wy) * (1.f - wx);
            w01 = (1.f - wy) * wx;
            w10 = wy * (1.f - wx);
            w11 = wy * wx;
            const bool vy0 = (y0 >= 0) & (y0 < 48), vy1 = (y1 >= 0) & (y1 < 48);
            const bool vx0 = (x0 >= 0) & (x0 < 48), vx1 = (x1 >= 0) & (x1 < 48);
            if (!(vy0 & vx0)) w00 = 0.f;
            if (!(vy0 & vx1)) w01 = 0.f;
            if (!(vy1 & vx0)) w10 = 0.f;
            if (!(vy1 & vx1)) w11 = 0.f;
            const int yc0 = min(max(y0, 0), 47), yc1 = min(max(y1, 0), 47);
            const int xc0 = min(max(x0, 0), 47), xc1 = min(max(x1, 0), 47);
            i00 = yc0 * 48 + xc0; i01 = yc0 * 48 + xc1;
            i10 = yc1 * 48 + xc0; i11 = yc1 * 48 + xc1;
        }
        const unsigned short* bb = xtt + cb;
        const uint4 u00 = *(const uint4*)(bb + i00 * 256);
        const uint4 u01 = *(const uint4*)(bb + i01 * 256);
        const uint4 u10 = *(const uint4*)(bb + i10 * 256);
        const uint4 u11 = *(const uint4*)(bb + i11 * 256);
        unsigned int pk[4];
        #pragma unroll
        for (int qi = 0; qi < 4; ++qi) {
            const unsigned int a  = ((const unsigned int*)&u00)[qi];
            const unsigned int b  = ((const unsigned int*)&u01)[qi];
            const unsigned int cc = ((const unsigned int*)&u10)[qi];
            const unsigned int dd = ((const unsigned int*)&u11)[qi];
            const float rl = w00 * bflo(a) + w01 * bflo(b) + w10 * bflo(cc) + w11 * bflo(dd);
            const float rh = w00 * bfhi(a) + w01 * bfhi(b) + w10 * bfhi(cc) + w11 * bfhi(dd);
            pk[qi] = (unsigned int)f2bf(rl) | ((unsigned int)f2bf(rh) << 16);
        }
        __syncthreads();
        gload16(Ap, la);
        gload16(Ap + arstep, la + 512);
        Ap += 64;
        *(uint4*)(Bsl + px * 32 + seg * 8) = make_uint4(pk[0], pk[1], pk[2], pk[3]);
        __syncthreads();
        mfma_step(Asl, Bsl, wm, wn, quad, l16, acc);
    }
    epilogue_atomic(Cf, m0, n0, wm, wn, quad, l16, C, acc);
}

extern "C" void kernel_launch(void* const* d_in, const int* in_sizes, int n_in,
                              void* d_out, int out_size, void* d_ws, size_t ws_size,
                              hipStream_t stream) {
    const float* x      = (const float*)d_in[0];
    const float* w_off  = (const float*)d_in[1];
    const float* w_def  = (const float*)d_in[2];
    const float* w_temp = (const float*)d_in[3];
    const float* b_temp = (const float*)d_in[4];
    float* out = (float*)d_out;

    // workspace (~24.2 MB)
    unsigned short* xt  = (unsigned short*)d_ws;                          //  4,718,592
    float*          offb = (float*)((char*)d_ws + 4718592ul);             //  9,437,184
    unsigned short* wbo = (unsigned short*)((char*)d_ws + 14155776ul);    //  3,276,800
    unsigned short* wbd = (unsigned short*)((char*)d_ws + 17432576ul);    //  3,276,800
    unsigned short* wbT = (unsigned short*)((char*)d_ws + 20709376ul);    //  3,538,944

    cast5_k<<<6400, 256, 0, stream>>>(w_off, wbo, OFFC);
    cast5_k<<<6400, 256, 0, stream>>>(w_def, wbd, C);
    cast_temp_k<<<6912, 256, 0, stream>>>(w_temp, wbT);
    xt_k<<<dim3(36, 4, T), 256, 0, stream>>>(x, xt);
    zero_k<<<2304, 256, 0, stream>>>(offb);
    fill_bias_k<<<2304, 256, 0, stream>>>(out, b_temp);

    gemm_off_k<<<dim3(144, 2, 2), 256, 0, stream>>>(wbo, xt, offb);
    gemm_temp_k<<<dim3(144, 2, 3), 256, 0, stream>>>(wbT, xt, out);
    gemm_def_k<<<dim3(144, 2, 2), 256, 0, stream>>>(wbd, xt, offb, out);
}

// Round 6
// 350.511 us; speedup vs baseline: 20.2976x; 1.1399x over previous
//
#include <hip/hip_runtime.h>
#include <hip/hip_bf16.h>

#define T    4
#define C    256
#define H    48
#define W    48
#define HW   2304
#define DG   4
#define OFFC 200
#define CK5  6400      // offset/deform K, (q,c) c-inner
#define CK9  2304      // temporal per-tap K, (j,c) c-inner
#define NFULL 9216     // T*HW

typedef __attribute__((ext_vector_type(8))) short bf16x8;
typedef __attribute__((ext_vector_type(4))) float f32x4;

__device__ __forceinline__ unsigned short f2bf(float f) {
    unsigned int u = __float_as_uint(f);
    return (unsigned short)((u + 0x7FFFu + ((u >> 16) & 1u)) >> 16);
}
__device__ __forceinline__ float bflo(unsigned int v) { return __uint_as_float(v << 16); }
__device__ __forceinline__ float bfhi(unsigned int v) { return __uint_as_float(v & 0xFFFF0000u); }
__device__ __forceinline__ unsigned int pack2(float lo, float hi) {
    __hip_bfloat162 h = __float22bfloat162_rn(make_float2(lo, hi));
    return *reinterpret_cast<unsigned int*>(&h);
}
__device__ __forceinline__ void gload16(const void* g, void* l) {
    __builtin_amdgcn_global_load_lds(
        (const __attribute__((address_space(1))) unsigned int*)g,
        (__attribute__((address_space(3))) unsigned int*)l, 16, 0, 0);
}

// ---------------------------------------------------------------------------
// Weight casts (fp32 -> bf16, K-major, c inner).
// ---------------------------------------------------------------------------
__global__ __launch_bounds__(256) void cast5_k(const float* __restrict__ w,
                                               unsigned short* __restrict__ a, int mvalid) {
    const int idx = blockIdx.x * 256 + threadIdx.x;      // < 256*6400
    const int c = idx & 255, rest = idx >> 8;
    const int q = rest % 25, o = rest / 25;
    a[(long)o * CK5 + q * 256 + c] =
        (o < mvalid) ? f2bf(w[((long)o * 256 + c) * 25 + q]) : (unsigned short)0;
}
// wbT[kt][o][(j,c)], j = kh*3+kw
__global__ __launch_bounds__(256) void cast_temp_k(const float* __restrict__ w,
                                                   unsigned short* __restrict__ a) {
    const int idx = blockIdx.x * 256 + threadIdx.x;      // < 3*256*2304
    const int c = idx & 255, rest = idx >> 8;
    const int j = rest % 9, oo = rest / 9;
    const int o = oo & 255, kt = oo >> 8;
    a[(long)kt * (256 * CK9) + (long)o * CK9 + j * 256 + c] =
        f2bf(w[((long)o * 256 + c) * 27 + kt * 9 + j]);
}

// offb zero + out bias-fill, fused.  grid 4608x256, float4 per thread.
__global__ __launch_bounds__(256) void fill_k(float* __restrict__ offb,
                                              float* __restrict__ out,
                                              const float* __restrict__ bias) {
    const long i = (long)blockIdx.x * 256 + threadIdx.x;   // < 1179648
    if (i < 589824) {
        ((float4*)offb)[i] = make_float4(0.f, 0.f, 0.f, 0.f);
    } else {
        const long j = i - 589824;
        const float b = bias[(int)(j / 2304)];
        ((float4*)out)[j] = make_float4(b, b, b, b);
    }
}

// ---------------------------------------------------------------------------
// x[c][t][p] fp32 -> xt[t][p][c] bf16 via LDS transpose. grid (36, 4 ct, T)
// ---------------------------------------------------------------------------
__global__ __launch_bounds__(256) void xt_k(const float* __restrict__ x,
                                            unsigned short* __restrict__ xt) {
    __shared__ float tile[64][65];
    const int p0 = blockIdx.x * 64, c0 = blockIdx.y * 64, t = blockIdx.z;
    const int px = threadIdx.x & 63, sub = threadIdx.x >> 6;
    for (int cl = sub; cl < 64; cl += 4)
        tile[px][cl] = x[((long)(c0 + cl) * T + t) * HW + p0 + px];
    __syncthreads();
    const int seg = sub * 16;
    unsigned int pk[8];
    #pragma unroll
    for (int d = 0; d < 8; ++d)
        pk[d] = (unsigned int)f2bf(tile[px][seg + d * 2]) |
                ((unsigned int)f2bf(tile[px][seg + d * 2 + 1]) << 16);
    unsigned short* orow = xt + ((long)t * HW + p0 + px) * 256 + c0 + seg;
    *(uint4*)(orow + 0) = make_uint4(pk[0], pk[1], pk[2], pk[3]);
    *(uint4*)(orow + 8) = make_uint4(pk[4], pk[5], pk[6], pk[7]);
}

// ---------------------------------------------------------------------------
// Shared MFMA iteration (BM=256, BN=64, BK=64).
// A LDS: 256 rows x 64 shorts, slots swizzled: row r holds global 16B-chunk q
//   at slot (q + (r&7)) & 7  (matches gload16 lane->slot mapping below).
// B LDS: 64 rows x 72 shorts (padded; k-chunk kh*32+quad*8 unswizzled).
// ---------------------------------------------------------------------------
__device__ __forceinline__ void mfma_iter(const unsigned short* __restrict__ Asl,
                                          const unsigned short* __restrict__ Bsl,
                                          int wave, int quad, int l16, f32x4 acc[4][4]) {
    #pragma unroll
    for (int kh = 0; kh < 2; ++kh) {
        bf16x8 af[4], bf[4];
        #pragma unroll
        for (int i = 0; i < 4; ++i) {
            const int row = wave * 64 + i * 16 + l16;
            const int slot = (kh * 4 + quad + (l16 & 7)) & 7;
            af[i] = *(const bf16x8*)(Asl + row * 64 + slot * 8);
        }
        #pragma unroll
        for (int j = 0; j < 4; ++j)
            bf[j] = *(const bf16x8*)(Bsl + (j * 16 + l16) * 72 + kh * 32 + quad * 8);
        #pragma unroll
        for (int i = 0; i < 4; ++i)
            #pragma unroll
            for (int j = 0; j < 4; ++j)
                acc[i][j] = __builtin_amdgcn_mfma_f32_16x16x32_bf16(af[i], bf[j], acc[i][j], 0, 0, 0);
    }
}
__device__ __forceinline__ void epilogue_atomic(float* __restrict__ Cf, int n0,
                                                int wave, int quad, int l16,
                                                int Mvalid, f32x4 acc[4][4]) {
    #pragma unroll
    for (int i = 0; i < 4; ++i)
        #pragma unroll
        for (int rr = 0; rr < 4; ++rr) {
            const int o = wave * 64 + i * 16 + quad * 4 + rr;
            if (o >= Mvalid) continue;
            #pragma unroll
            for (int j = 0; j < 4; ++j)
                unsafeAtomicAdd(Cf + (long)o * NFULL + n0 + j * 16 + l16, acc[i][j][rr]);
        }
}

__device__ __forceinline__ void pos_calc(int h, int w, int q, float dy, float dx,
                                         float& w00, float& w01, float& w10, float& w11,
                                         int& i00, int& i01, int& i10, int& i11) {
    const int qy = q / 5, qx = q - qy * 5;
    const float sy = (float)(h + qy - 2) + dy;
    const float sx = (float)(w + qx - 2) + dx;
    const float y0f = floorf(sy), x0f = floorf(sx);
    const float wy = sy - y0f, wx = sx - x0f;
    const int y0 = (int)y0f, x0 = (int)x0f;
    const int y1 = y0 + 1, x1 = x0 + 1;
    w00 = (1.f - wy) * (1.f - wx);
    w01 = (1.f - wy) * wx;
    w10 = wy * (1.f - wx);
    w11 = wy * wx;
    const bool vy0 = (y0 >= 0) & (y0 < 48), vy1 = (y1 >= 0) & (y1 < 48);
    const bool vx0 = (x0 >= 0) & (x0 < 48), vx1 = (x1 >= 0) & (x1 < 48);
    if (!(vy0 & vx0)) w00 = 0.f;
    if (!(vy0 & vx1)) w01 = 0.f;
    if (!(vy1 & vx0)) w10 = 0.f;
    if (!(vy1 & vx1)) w11 = 0.f;
    const int yc0 = min(max(y0, 0), 47), yc1 = min(max(y1, 0), 47);
    const int xc0 = min(max(x0, 0), 47), xc1 = min(max(x1, 0), 47);
    i00 = yc0 * 48 + xc0; i01 = yc0 * 48 + xc1;
    i10 = yc1 * 48 + xc0; i11 = yc1 * 48 + xc1;
}

__device__ __forceinline__ void blend4(const uint4& ua, const uint4& ub,
                                       const uint4& uc, const uint4& ud,
                                       float w00, float w01, float w10, float w11,
                                       uint4& outp) {
    unsigned int pk[4];
    #pragma unroll
    for (int qi = 0; qi < 4; ++qi) {
        const unsigned int a = ((const unsigned int*)&ua)[qi];
        const unsigned int b = ((const unsigned int*)&ub)[qi];
        const unsigned int c = ((const unsigned int*)&uc)[qi];
        const unsigned int d = ((const unsigned int*)&ud)[qi];
        const float rl = w00 * bflo(a) + w01 * bflo(b) + w10 * bflo(c) + w11 * bflo(d);
        const float rh = w00 * bfhi(a) + w01 * bfhi(b) + w10 * bfhi(c) + w11 * bfhi(d);
        pk[qi] = pack2(rl, rh);
    }
    outp = make_uint4(pk[0], pk[1], pk[2], pk[3]);
}

// ---------------------------------------------------------------------------
// Implicit offset-conv GEMM.  grid (144, 1, 4): kLen=1600, 25 iters.
// ---------------------------------------------------------------------------
__global__ __launch_bounds__(256) void gemm_off_k(const unsigned short* __restrict__ A,
                                                  const unsigned short* __restrict__ xt,
                                                  float* __restrict__ Cf) {
    __shared__ unsigned short Asl[256 * 64];
    __shared__ unsigned short Bsl[64 * 72];
    const int tid = threadIdx.x;
    const int wave = tid >> 6, lane = tid & 63;
    const int quad = lane >> 4, l16 = lane & 15;
    const int n0 = blockIdx.x * 64, k0 = blockIdx.z * 1600;
    const int t = n0 / HW, p0 = n0 - t * HW;

    const int r8 = lane >> 3, s8 = lane & 7;
    const int qg = (s8 - r8) & 7;                 // A slot swizzle (see mfma_iter)
    const long ldAb = (long)CK5 * 2;
    const char* Ap = (const char*)A + (long)(wave * 64 + r8) * ldAb + (long)k0 * 2 + qg * 16;
    const long rstep8 = 8 * ldAb;
    unsigned short* la = Asl + wave * 4096;

    const int px = tid >> 2, seg = tid & 3;
    const int p = p0 + px, h = p / 48, w = p - h * 48;
    const unsigned short* xtt = xt + (long)t * HW * 256 + seg * 8;

    uint4 cv0 = make_uint4(0, 0, 0, 0), cv1 = cv0;
    {
        const int q = k0 >> 8, cb = k0 & 255;
        const int qy = q / 5, qx = q - qy * 5;
        const int y = h + qy - 2, xx = w + qx - 2;
        if ((y >= 0) & (y < 48) & (xx >= 0) & (xx < 48)) {
            const unsigned short* bp = xtt + (y * 48 + xx) * 256 + cb;
            cv0 = *(const uint4*)bp; cv1 = *(const uint4*)(bp + 32);
        }
    }

    f32x4 acc[4][4] = {};
    for (int i = 0; i < 25; ++i) {
        __syncthreads();
        #pragma unroll
        for (int c2 = 0; c2 < 8; ++c2) gload16(Ap + c2 * rstep8, la + c2 * 512);
        Ap += 128;
        *(uint4*)(Bsl + px * 72 + seg * 8)      = cv0;
        *(uint4*)(Bsl + px * 72 + 32 + seg * 8) = cv1;
        uint4 nv0 = make_uint4(0, 0, 0, 0), nv1 = nv0;
        if (i + 1 < 25) {
            const int kk2 = k0 + (i + 1) * 64;
            const int q = kk2 >> 8, cb = kk2 & 255;
            const int qy = q / 5, qx = q - qy * 5;
            const int y = h + qy - 2, xx = w + qx - 2;
            if ((y >= 0) & (y < 48) & (xx >= 0) & (xx < 48)) {
                const unsigned short* bp = xtt + (y * 48 + xx) * 256 + cb;
                nv0 = *(const uint4*)bp; nv1 = *(const uint4*)(bp + 32);
            }
        }
        __syncthreads();
        mfma_iter(Asl, Bsl, wave, quad, l16, acc);
        cv0 = nv0; cv1 = nv1;
    }
    epilogue_atomic(Cf, n0, wave, quad, l16, OFFC, acc);
}

// ---------------------------------------------------------------------------
// Implicit temporal GEMM.  grid (144, 1, 6): z = tap*2 + half, 18 iters.
// ---------------------------------------------------------------------------
__global__ __launch_bounds__(256) void gemm_temp_k(const unsigned short* __restrict__ AT,
                                                   const unsigned short* __restrict__ xt,
                                                   float* __restrict__ Cf) {
    const int n0 = blockIdx.x * 64;
    const int kt = blockIdx.z >> 1, half = blockIdx.z & 1;
    const int t = n0 / HW, tsrc = t + kt - 1;
    if (tsrc < 0 || tsrc >= T) return;

    __shared__ unsigned short Asl[256 * 64];
    __shared__ unsigned short Bsl[64 * 72];
    const int tid = threadIdx.x;
    const int wave = tid >> 6, lane = tid & 63;
    const int quad = lane >> 4, l16 = lane & 15;
    const int k0 = half * 1152;
    const int p0 = n0 - t * HW;

    const int r8 = lane >> 3, s8 = lane & 7;
    const int qg = (s8 - r8) & 7;
    const long ldAb = (long)CK9 * 2;
    const char* Ap = (const char*)(AT + (long)kt * 256 * CK9)
                     + (long)(wave * 64 + r8) * ldAb + (long)k0 * 2 + qg * 16;
    const long rstep8 = 8 * ldAb;
    unsigned short* la = Asl + wave * 4096;

    const int px = tid >> 2, seg = tid & 3;
    const int p = p0 + px, h = p / 48, w = p - h * 48;
    const unsigned short* xtt = xt + (long)tsrc * HW * 256 + seg * 8;

    uint4 cv0 = make_uint4(0, 0, 0, 0), cv1 = cv0;
    {
        const int j = k0 >> 8, cb = k0 & 255;
        const int jy = j / 3, jx = j - jy * 3;
        const int y = h + jy - 1, xx = w + jx - 1;
        if ((y >= 0) & (y < 48) & (xx >= 0) & (xx < 48)) {
            const unsigned short* bp = xtt + (y * 48 + xx) * 256 + cb;
            cv0 = *(const uint4*)bp; cv1 = *(const uint4*)(bp + 32);
        }
    }

    f32x4 acc[4][4] = {};
    for (int i = 0; i < 18; ++i) {
        __syncthreads();
        #pragma unroll
        for (int c2 = 0; c2 < 8; ++c2) gload16(Ap + c2 * rstep8, la + c2 * 512);
        Ap += 128;
        *(uint4*)(Bsl + px * 72 + seg * 8)      = cv0;
        *(uint4*)(Bsl + px * 72 + 32 + seg * 8) = cv1;
        uint4 nv0 = make_uint4(0, 0, 0, 0), nv1 = nv0;
        if (i + 1 < 18) {
            const int kk2 = k0 + (i + 1) * 64;
            const int j = kk2 >> 8, cb = kk2 & 255;
            const int jy = j / 3, jx = j - jy * 3;
            const int y = h + jy - 1, xx = w + jx - 1;
            if ((y >= 0) & (y < 48) & (xx >= 0) & (xx < 48)) {
                const unsigned short* bp = xtt + (y * 48 + xx) * 256 + cb;
                nv0 = *(const uint4*)bp; nv1 = *(const uint4*)(bp + 32);
            }
        }
        __syncthreads();
        mfma_iter(Asl, Bsl, wave, quad, l16, acc);
        cv0 = nv0; cv1 = nv1;
    }
    epilogue_atomic(Cf, n0, wave, quad, l16, C, acc);
}

// ---------------------------------------------------------------------------
// Implicit deformable GEMM.  grid (144, 1, 4): kLen=1600, 25 iters.
// One (q,g) group per 64-k iter; dy/dx prefetched 2 iters ahead, corners 1
// iter ahead, blend overlapped with MFMA.
// ---------------------------------------------------------------------------
__global__ __launch_bounds__(256) void gemm_def_k(const unsigned short* __restrict__ A,
                                                  const unsigned short* __restrict__ xt,
                                                  const float* __restrict__ offb,
                                                  float* __restrict__ Cf) {
    __shared__ unsigned short Asl[256 * 64];
    __shared__ unsigned short Bsl[64 * 72];
    const int tid = threadIdx.x;
    const int wave = tid >> 6, lane = tid & 63;
    const int quad = lane >> 4, l16 = lane & 15;
    const int n0 = blockIdx.x * 64, k0 = blockIdx.z * 1600;
    const int t = n0 / HW, p0 = n0 - t * HW;

    const int r8 = lane >> 3, s8 = lane & 7;
    const int qg = (s8 - r8) & 7;
    const long ldAb = (long)CK5 * 2;
    const char* Ap = (const char*)A + (long)(wave * 64 + r8) * ldAb + (long)k0 * 2 + qg * 16;
    const long rstep8 = 8 * ldAb;
    unsigned short* la = Asl + wave * 4096;

    const int px = tid >> 2, seg = tid & 3;
    const int p = p0 + px, h = p / 48, w = p - h * 48;
    const int nabs = n0 + px;
    const unsigned short* xtt = xt + (long)t * HW * 256 + seg * 8;

    uint4 pkv0, pkv1;
    float dyA, dxA;
    {   // iter 0: position + corners + blend; prefetch dy/dx for iter 1
        const int q = k0 >> 8, cb = k0 & 255, g = cb >> 6;
        const float dy = offb[(long)(g * 50 + 2 * q) * NFULL + nabs];
        const float dx = offb[(long)(g * 50 + 2 * q + 1) * NFULL + nabs];
        float w00, w01, w10, w11; int i00, i01, i10, i11;
        pos_calc(h, w, q, dy, dx, w00, w01, w10, w11, i00, i01, i10, i11);
        const unsigned short* b00 = xtt + i00 * 256 + cb;
        const unsigned short* b01 = xtt + i01 * 256 + cb;
        const unsigned short* b10 = xtt + i10 * 256 + cb;
        const unsigned short* b11 = xtt + i11 * 256 + cb;
        blend4(*(const uint4*)b00, *(const uint4*)b01,
               *(const uint4*)b10, *(const uint4*)b11, w00, w01, w10, w11, pkv0);
        blend4(*(const uint4*)(b00 + 32), *(const uint4*)(b01 + 32),
               *(const uint4*)(b10 + 32), *(const uint4*)(b11 + 32), w00, w01, w10, w11, pkv1);
        const int kk1 = k0 + 64;
        const int q1 = kk1 >> 8, g1 = (kk1 & 255) >> 6;
        dyA = offb[(long)(g1 * 50 + 2 * q1) * NFULL + nabs];
        dxA = offb[(long)(g1 * 50 + 2 * q1 + 1) * NFULL + nabs];
    }

    f32x4 acc[4][4] = {};
    for (int i = 0; i < 25; ++i) {
        __syncthreads();
        #pragma unroll
        for (int c2 = 0; c2 < 8; ++c2) gload16(Ap + c2 * rstep8, la + c2 * 512);
        Ap += 128;
        *(uint4*)(Bsl + px * 72 + seg * 8)      = pkv0;
        *(uint4*)(Bsl + px * 72 + 32 + seg * 8) = pkv1;

        uint4 n00a, n01a, n10a, n11a, n00b, n01b, n10b, n11b;
        float nw00, nw01, nw10, nw11;
        const bool more = (i + 1 < 25);
        if (more) {
            const int kk2 = k0 + (i + 1) * 64;
            const int q2 = kk2 >> 8, cb2 = kk2 & 255;
            int i00, i01, i10, i11;
            pos_calc(h, w, q2, dyA, dxA, nw00, nw01, nw10, nw11, i00, i01, i10, i11);
            const unsigned short* b00 = xtt + i00 * 256 + cb2;
            const unsigned short* b01 = xtt + i01 * 256 + cb2;
            const unsigned short* b10 = xtt + i10 * 256 + cb2;
            const unsigned short* b11 = xtt + i11 * 256 + cb2;
            n00a = *(const uint4*)b00; n00b = *(const uint4*)(b00 + 32);
            n01a = *(const uint4*)b01; n01b = *(const uint4*)(b01 + 32);
            n10a = *(const uint4*)b10; n10b = *(const uint4*)(b10 + 32);
            n11a = *(const uint4*)b11; n11b = *(const uint4*)(b11 + 32);
            if (i + 2 < 25) {
                const int kk3 = kk2 + 64;
                const int q3 = kk3 >> 8, g3 = (kk3 & 255) >> 6;
                dyA = offb[(long)(g3 * 50 + 2 * q3) * NFULL + nabs];
                dxA = offb[(long)(g3 * 50 + 2 * q3 + 1) * NFULL + nabs];
            }
        }
        __syncthreads();
        mfma_iter(Asl, Bsl, wave, quad, l16, acc);
        if (more) {
            blend4(n00a, n01a, n10a, n11a, nw00, nw01, nw10, nw11, pkv0);
            blend4(n00b, n01b, n10b, n11b, nw00, nw01, nw10, nw11, pkv1);
        }
    }
    epilogue_atomic(Cf, n0, wave, quad, l16, C, acc);
}

extern "C" void kernel_launch(void* const* d_in, const int* in_sizes, int n_in,
                              void* d_out, int out_size, void* d_ws, size_t ws_size,
                              hipStream_t stream) {
    const float* x      = (const float*)d_in[0];
    const float* w_off  = (const float*)d_in[1];
    const float* w_def  = (const float*)d_in[2];
    const float* w_temp = (const float*)d_in[3];
    const float* b_temp = (const float*)d_in[4];
    float* out = (float*)d_out;

    // workspace (~24.2 MB)
    unsigned short* xt   = (unsigned short*)d_ws;                         //  4,718,592
    float*          offb = (float*)((char*)d_ws + 4718592ul);             //  9,437,184
    unsigned short* wbo  = (unsigned short*)((char*)d_ws + 14155776ul);   //  3,276,800
    unsigned short* wbd  = (unsigned short*)((char*)d_ws + 17432576ul);   //  3,276,800
    unsigned short* wbT  = (unsigned short*)((char*)d_ws + 20709376ul);   //  3,538,944

    cast5_k<<<6400, 256, 0, stream>>>(w_off, wbo, OFFC);
    cast5_k<<<6400, 256, 0, stream>>>(w_def, wbd, C);
    cast_temp_k<<<6912, 256, 0, stream>>>(w_temp, wbT);
    xt_k<<<dim3(36, 4, T), 256, 0, stream>>>(x, xt);
    fill_k<<<4608, 256, 0, stream>>>(offb, out, b_temp);

    gemm_off_k<<<dim3(144, 1, 4), 256, 0, stream>>>(wbo, xt, offb);
    gemm_temp_k<<<dim3(144, 1, 6), 256, 0, stream>>>(wbT, xt, out);
    gemm_def_k<<<dim3(144, 1, 4), 256, 0, stream>>>(wbd, xt, offb, out);
}